// Round 1
// baseline (9957.104 us; speedup 1.0000x reference)
//
#include <hip/hip_runtime.h>

#define NN 100000
#define NE 3200000
#define HID 128
#define CH 25000   // MLP row-chunk

// ---------------- small utility kernels ----------------
__global__ void zero_k(int* p, int n) {
    int i = blockIdx.x * 256 + threadIdx.x;
    if (i < n) p[i] = 0;
}

__global__ void copyi_k(const int* __restrict__ a, int* __restrict__ b, int n) {
    int i = blockIdx.x * 256 + threadIdx.x;
    if (i < n) b[i] = a[i];
}

__global__ void hist_k(const int* __restrict__ dst, int* __restrict__ cnt) {
    int e = blockIdx.x * 256 + threadIdx.x;
    if (e < NE) atomicAdd(&cnt[dst[e]], 1);
}

// single-block exclusive scan of rowptr[0..n), writes rowptr[n]=total
__global__ void scan_k(int* __restrict__ rowptr, int n) {
    __shared__ int wsum[16];
    int tid = threadIdx.x;
    int lane = tid & 63, wid = tid >> 6;
    int carry = 0;
    for (int base = 0; base < n; base += 1024) {
        int idx = base + tid;
        int v = (idx < n) ? rowptr[idx] : 0;
        int s = v;
#pragma unroll
        for (int o = 1; o < 64; o <<= 1) {
            int t = __shfl_up(s, o, 64);
            if (lane >= o) s += t;
        }
        if (lane == 63) wsum[wid] = s;
        __syncthreads();
        if (wid == 0) {
            int ws = (lane < 16) ? wsum[lane] : 0;
#pragma unroll
            for (int o = 1; o < 16; o <<= 1) {
                int t = __shfl_up(ws, o, 64);
                if (lane >= o) ws += t;
            }
            if (lane < 16) wsum[lane] = ws;
        }
        __syncthreads();
        int woff = (wid == 0) ? 0 : wsum[wid - 1];
        int excl = carry + woff + s - v;
        if (idx < n) rowptr[idx] = excl;
        carry += wsum[15];
        __syncthreads();
    }
    if (tid == 0) rowptr[n] = carry;
}

__global__ void scatter_k(const int* __restrict__ src, const int* __restrict__ dst,
                          const float* __restrict__ w, int* __restrict__ cursor,
                          int* __restrict__ esrc, float* __restrict__ ew) {
    int e = blockIdx.x * 256 + threadIdx.x;
    if (e < NE) {
        int d = dst[e];
        int pos = atomicAdd(&cursor[d], 1);
        esrc[pos] = src[e];
        ew[pos] = w[e];
    }
}

// ---------------- SpMM (CSR) + bias + relu (+ l2norm) + xsum accumulate ----------------
// one wave per dst row; lane holds cols {2*lane, 2*lane+1}
template <bool NORM, bool INITSUM>
__global__ void spmm_k(const float* __restrict__ x, const int* __restrict__ rowptr,
                       const int* __restrict__ esrc, const float* __restrict__ ew,
                       const float* __restrict__ bias, float* __restrict__ outx,
                       float* __restrict__ xsum) {
    int row = blockIdx.x * 4 + (threadIdx.x >> 6);
    int lane = threadIdx.x & 63;
    if (row >= NN) return;
    int e0 = rowptr[row], e1 = rowptr[row + 1];
    float ax = 0.f, ay = 0.f;
    for (int e = e0; e < e1; ++e) {
        int s = esrc[e];
        float w = ew[e];
        float2 v = ((const float2*)(x + (size_t)s * HID))[lane];
        ax += w * v.x;
        ay += w * v.y;
    }
    ax = fmaxf(ax + bias[lane * 2], 0.f);
    ay = fmaxf(ay + bias[lane * 2 + 1], 0.f);
    if (NORM) {
        float ss = ax * ax + ay * ay;
#pragma unroll
        for (int o = 32; o >= 1; o >>= 1) ss += __shfl_xor(ss, o, 64);
        float nrm = sqrtf(ss);
        float sc = 1.0f / fmaxf(nrm, 1e-12f);
        ax *= sc;
        ay *= sc;
    }
    ((float2*)(outx + (size_t)row * HID))[lane] = make_float2(ax, ay);
    float2* srow = (float2*)(xsum + (size_t)row * HID);
    if (INITSUM) {
        srow[lane] = make_float2(ax, ay);
    } else {
        float2 p = srow[lane];
        srow[lane] = make_float2(p.x + ax, p.y + ay);
    }
}

// ---------------- C[M x 128] = A[M x 128] @ B[128 x 128] ----------------
__global__ __launch_bounds__(256) void gemm128_k(const float* __restrict__ A,
                                                 const float* __restrict__ B,
                                                 float* __restrict__ C, int M) {
    __shared__ float As[64][32];
    __shared__ float Bs[32][128];
    int t = threadIdx.x;
    int tx = t & 31, ty = t >> 5;
    int rowBase = blockIdx.x * 64;
    float acc[8][4] = {};
    for (int k0 = 0; k0 < 128; k0 += 32) {
#pragma unroll
        for (int i = 0; i < 2; ++i) {
            int idx = t + i * 256;
            int r = idx >> 3, c4 = idx & 7;
            int gr = rowBase + r;
            float4 v = (gr < M) ? ((const float4*)(A + (size_t)gr * 128 + k0))[c4]
                                : make_float4(0.f, 0.f, 0.f, 0.f);
            *((float4*)&As[r][c4 * 4]) = v;
        }
#pragma unroll
        for (int i = 0; i < 4; ++i) {
            int idx = t + i * 256;
            int r = idx >> 5, c4 = idx & 31;
            *((float4*)&Bs[r][c4 * 4]) = ((const float4*)(B + (size_t)(k0 + r) * 128))[c4];
        }
        __syncthreads();
#pragma unroll
        for (int kk = 0; kk < 32; ++kk) {
            float4 b = *((const float4*)&Bs[kk][tx * 4]);
#pragma unroll
            for (int r = 0; r < 8; ++r) {
                float a = As[ty * 8 + r][kk];
                acc[r][0] += a * b.x;
                acc[r][1] += a * b.y;
                acc[r][2] += a * b.z;
                acc[r][3] += a * b.w;
            }
        }
        __syncthreads();
    }
#pragma unroll
    for (int r = 0; r < 8; ++r) {
        int gr = rowBase + ty * 8 + r;
        if (gr < M)
            *((float4*)(C + (size_t)gr * 128 + tx * 4)) =
                make_float4(acc[r][0], acc[r][1], acc[r][2], acc[r][3]);
    }
}

// ---------------- hmlp = relu(A[M x 128] @ L1[128 x 256] + bl1), chunk rows [row0,row1) ----------------
__global__ __launch_bounds__(256) void gemm256_k(const float* __restrict__ A,
                                                 const float* __restrict__ B,
                                                 const float* __restrict__ bias,
                                                 float* __restrict__ C, int row0, int row1) {
    __shared__ float As[32][32];
    __shared__ float Bs[32][256];
    int t = threadIdx.x;
    int tx = t & 63, ty = t >> 6;
    int rowBase = row0 + blockIdx.x * 32;
    float acc[8][4] = {};
    for (int k0 = 0; k0 < 128; k0 += 32) {
        {
            int r = t >> 3, c4 = t & 7;
            int gr = rowBase + r;
            float4 v = (gr < row1) ? ((const float4*)(A + (size_t)gr * 128 + k0))[c4]
                                   : make_float4(0.f, 0.f, 0.f, 0.f);
            *((float4*)&As[r][c4 * 4]) = v;
        }
#pragma unroll
        for (int i = 0; i < 8; ++i) {
            int idx = t + i * 256;
            int r = idx >> 6, c4 = idx & 63;
            *((float4*)&Bs[r][c4 * 4]) = ((const float4*)(B + (size_t)(k0 + r) * 256))[c4];
        }
        __syncthreads();
#pragma unroll
        for (int kk = 0; kk < 32; ++kk) {
            float4 b = *((const float4*)&Bs[kk][tx * 4]);
#pragma unroll
            for (int r = 0; r < 8; ++r) {
                float a = As[ty * 8 + r][kk];
                acc[r][0] += a * b.x;
                acc[r][1] += a * b.y;
                acc[r][2] += a * b.z;
                acc[r][3] += a * b.w;
            }
        }
        __syncthreads();
    }
    float4 bb = *((const float4*)&bias[tx * 4]);
#pragma unroll
    for (int r = 0; r < 8; ++r) {
        int gr = rowBase + ty * 8 + r;
        if (gr < row1) {
            float4 v = make_float4(fmaxf(acc[r][0] + bb.x, 0.f), fmaxf(acc[r][1] + bb.y, 0.f),
                                   fmaxf(acc[r][2] + bb.z, 0.f), fmaxf(acc[r][3] + bb.w, 0.f));
            *((float4*)(C + (size_t)(gr - row0) * 256 + tx * 4)) = v;
        }
    }
}

// ---------------- sacc[r] += relu(hmlp[r] @ L2 + bl2) . L3 + bl3 ----------------
__global__ __launch_bounds__(256) void mlp2_k(const float* __restrict__ A,  // chunk-local rows x 256
                                              const float* __restrict__ B,  // L2 256x256
                                              const float* __restrict__ bias,
                                              const float* __restrict__ L3,
                                              const float* __restrict__ bl3,
                                              float* __restrict__ sacc, int row0, int row1) {
    __shared__ float As[32][32];
    __shared__ float Bs[32][256];
    int t = threadIdx.x;
    int tx = t & 63, ty = t >> 6;
    int rowBase = row0 + blockIdx.x * 32;
    float acc[8][4] = {};
    for (int k0 = 0; k0 < 256; k0 += 32) {
        {
            int r = t >> 3, c4 = t & 7;
            int gr = rowBase + r;
            float4 v = (gr < row1) ? ((const float4*)(A + (size_t)(gr - row0) * 256 + k0))[c4]
                                   : make_float4(0.f, 0.f, 0.f, 0.f);
            *((float4*)&As[r][c4 * 4]) = v;
        }
#pragma unroll
        for (int i = 0; i < 8; ++i) {
            int idx = t + i * 256;
            int r = idx >> 6, c4 = idx & 63;
            *((float4*)&Bs[r][c4 * 4]) = ((const float4*)(B + (size_t)(k0 + r) * 256))[c4];
        }
        __syncthreads();
#pragma unroll
        for (int kk = 0; kk < 32; ++kk) {
            float4 b = *((const float4*)&Bs[kk][tx * 4]);
#pragma unroll
            for (int r = 0; r < 8; ++r) {
                float a = As[ty * 8 + r][kk];
                acc[r][0] += a * b.x;
                acc[r][1] += a * b.y;
                acc[r][2] += a * b.z;
                acc[r][3] += a * b.w;
            }
        }
        __syncthreads();
    }
    float4 bb = *((const float4*)&bias[tx * 4]);
    float4 l3 = *((const float4*)&L3[tx * 4]);
    float b3 = *bl3;
#pragma unroll
    for (int r = 0; r < 8; ++r) {
        float h0 = fmaxf(acc[r][0] + bb.x, 0.f);
        float h1 = fmaxf(acc[r][1] + bb.y, 0.f);
        float h2 = fmaxf(acc[r][2] + bb.z, 0.f);
        float h3 = fmaxf(acc[r][3] + bb.w, 0.f);
        float p = h0 * l3.x + h1 * l3.y + h2 * l3.z + h3 * l3.w;
#pragma unroll
        for (int o = 32; o >= 1; o >>= 1) p += __shfl_xor(p, o, 64);
        int gr = rowBase + ty * 8 + r;
        if (gr < row1 && tx == 0) sacc[gr] += p + b3;
    }
}

__global__ void score_store_k(const float* __restrict__ sacc, float* __restrict__ dst) {
    int i = blockIdx.x * 256 + threadIdx.x;
    if (i < NN) dst[i] = sacc[i] * (1.f / 7.f);
}

__global__ void final_mul_k(const float* __restrict__ sacc, const float* __restrict__ score1,
                            float* __restrict__ out) {
    int i = blockIdx.x * 256 + threadIdx.x;
    if (i < NN) out[i] = score1[i] * (sacc[i] * (1.f / 7.f));
}

// ---------------- host orchestration ----------------
extern "C" void kernel_launch(void* const* d_in, const int* in_sizes, int n_in,
                              void* d_out, int out_size, void* d_ws, size_t ws_size,
                              hipStream_t stream) {
    const int* asrc[2] = {(const int*)d_in[0], (const int*)d_in[3]};
    const int* adst[2] = {(const int*)d_in[1], (const int*)d_in[4]};
    const float* aw[2] = {(const float*)d_in[2], (const float*)d_in[5]};
    const float* W1 = (const float*)d_in[6];
    const float* b1 = (const float*)d_in[7];
    const float* Wk[5] = {(const float*)d_in[8], (const float*)d_in[10], (const float*)d_in[12],
                          (const float*)d_in[14], (const float*)d_in[16]};
    const float* bk[5] = {(const float*)d_in[9], (const float*)d_in[11], (const float*)d_in[13],
                          (const float*)d_in[15], (const float*)d_in[17]};
    const float* L1 = (const float*)d_in[18];
    const float* bl1 = (const float*)d_in[19];
    const float* L2 = (const float*)d_in[20];
    const float* bl2 = (const float*)d_in[21];
    const float* L3 = (const float*)d_in[22];
    const float* bl3 = (const float*)d_in[23];
    float* out = (float*)d_out;

    // workspace layout (floats/ints, all 4B)
    float* ws = (float*)d_ws;
    float* cur = ws;                       // N*128
    float* tmp = cur + (size_t)NN * HID;   // N*128
    float* xsum = tmp + (size_t)NN * HID;  // N*128
    float* hmlp = xsum + (size_t)NN * HID; // CH*256
    float* sacc = hmlp + (size_t)CH * 256; // N
    float* score1 = sacc + NN;             // N
    int* rowptr = (int*)(score1 + NN);     // N+1
    int* cursor = rowptr + (NN + 1);       // N
    int* esrc = cursor + NN;               // E
    float* ew = (float*)(esrc + NE);       // E

    const int GE = (NE + 255) / 256;    // 12500
    const int GN = (NN + 255) / 256;    // 391
    const int GS = (NN + 3) / 4;        // 25000 (spmm)
    const int GG = (NN + 63) / 64;      // 1563 (gemm128)

    for (int br = 0; br < 2; ++br) {
        // ---- build CSR ----
        zero_k<<<GN, 256, 0, stream>>>(rowptr, NN + 1);
        hist_k<<<GE, 256, 0, stream>>>(adst[br], rowptr);
        scan_k<<<1, 1024, 0, stream>>>(rowptr, NN);
        copyi_k<<<GN, 256, 0, stream>>>(rowptr, cursor, NN);
        scatter_k<<<GE, 256, 0, stream>>>(asrc[br], adst[br], aw[br], cursor, esrc, ew);

        zero_k<<<GN, 256, 0, stream>>>((int*)sacc, NN);

        // ---- layer 1: x1 = norm(relu(spmm(W1)+b1)) ----
        spmm_k<true, true><<<GS, 256, 0, stream>>>(W1, rowptr, esrc, ew, b1, cur, xsum);
        // mlp(x1)
        for (int c0 = 0; c0 < NN; c0 += CH) {
            int c1 = (c0 + CH < NN) ? c0 + CH : NN;
            int nb = (c1 - c0 + 31) / 32;
            gemm256_k<<<nb, 256, 0, stream>>>(cur, L1, bl1, hmlp, c0, c1);
            mlp2_k<<<nb, 256, 0, stream>>>(hmlp, L2, bl2, L3, bl3, sacc, c0, c1);
        }

        // ---- layers 2..6 ----
        for (int l = 0; l < 5; ++l) {
            gemm128_k<<<GG, 256, 0, stream>>>(cur, Wk[l], tmp, NN);
            if (l < 4)
                spmm_k<true, false><<<GS, 256, 0, stream>>>(tmp, rowptr, esrc, ew, bk[l], cur, xsum);
            else
                spmm_k<false, false><<<GS, 256, 0, stream>>>(tmp, rowptr, esrc, ew, bk[l], cur, xsum);
            for (int c0 = 0; c0 < NN; c0 += CH) {
                int c1 = (c0 + CH < NN) ? c0 + CH : NN;
                int nb = (c1 - c0 + 31) / 32;
                gemm256_k<<<nb, 256, 0, stream>>>(cur, L1, bl1, hmlp, c0, c1);
                mlp2_k<<<nb, 256, 0, stream>>>(hmlp, L2, bl2, L3, bl3, sacc, c0, c1);
            }
        }

        // ---- mlp(x7 = xsum) ----
        for (int c0 = 0; c0 < NN; c0 += CH) {
            int c1 = (c0 + CH < NN) ? c0 + CH : NN;
            int nb = (c1 - c0 + 31) / 32;
            gemm256_k<<<nb, 256, 0, stream>>>(xsum, L1, bl1, hmlp, c0, c1);
            mlp2_k<<<nb, 256, 0, stream>>>(hmlp, L2, bl2, L3, bl3, sacc, c0, c1);
        }

        if (br == 0)
            score_store_k<<<GN, 256, 0, stream>>>(sacc, score1);
        else
            final_mul_k<<<GN, 256, 0, stream>>>(sacc, score1, out);
    }
}

// Round 3
// 5287.899 us; speedup vs baseline: 1.8830x; 1.8830x over previous
//
#include <hip/hip_runtime.h>

#define NN 100000
#define NE 3200000
#define HID 128

typedef __attribute__((ext_vector_type(8))) _Float16 f16x8;
typedef __attribute__((ext_vector_type(4))) _Float16 f16x4;
typedef __attribute__((ext_vector_type(2))) _Float16 f16x2;
typedef __attribute__((ext_vector_type(4))) float f32x4;

// swizzle in element units: XOR elem bits 3..5 with row bits 0..2
#define SWZ(row, k) ((k) ^ (((row) & 7) << 3))

// ---------------- small utility kernels ----------------
__global__ void zero_k(int* p, int n) {
    int i = blockIdx.x * 256 + threadIdx.x;
    if (i < n) p[i] = 0;
}

__global__ void copyi_k(const int* __restrict__ a, int* __restrict__ b, int n) {
    int i = blockIdx.x * 256 + threadIdx.x;
    if (i < n) b[i] = a[i];
}

__global__ void hist_k(const int* __restrict__ dst, int* __restrict__ cnt) {
    int e = blockIdx.x * 256 + threadIdx.x;
    if (e < NE) atomicAdd(&cnt[dst[e]], 1);
}

// single-block exclusive scan of rowptr[0..n), writes rowptr[n]=total
__global__ void scan_k(int* __restrict__ rowptr, int n) {
    __shared__ int wsum[16];
    int tid = threadIdx.x;
    int lane = tid & 63, wid = tid >> 6;
    int carry = 0;
    for (int base = 0; base < n; base += 1024) {
        int idx = base + tid;
        int v = (idx < n) ? rowptr[idx] : 0;
        int s = v;
#pragma unroll
        for (int o = 1; o < 64; o <<= 1) {
            int t = __shfl_up(s, o, 64);
            if (lane >= o) s += t;
        }
        if (lane == 63) wsum[wid] = s;
        __syncthreads();
        if (wid == 0) {
            int ws = (lane < 16) ? wsum[lane] : 0;
#pragma unroll
            for (int o = 1; o < 16; o <<= 1) {
                int t = __shfl_up(ws, o, 64);
                if (lane >= o) ws += t;
            }
            if (lane < 16) wsum[lane] = ws;
        }
        __syncthreads();
        int woff = (wid == 0) ? 0 : wsum[wid - 1];
        int excl = carry + woff + s - v;
        if (idx < n) rowptr[idx] = excl;
        carry += wsum[15];
        __syncthreads();
    }
    if (tid == 0) rowptr[n] = carry;
}

__global__ void scatter_k(const int* __restrict__ src, const int* __restrict__ dst,
                          const float* __restrict__ w, int* __restrict__ cursor,
                          int* __restrict__ esrc, float* __restrict__ ew) {
    int e = blockIdx.x * 256 + threadIdx.x;
    if (e < NE) {
        int d = dst[e];
        int pos = atomicAdd(&cursor[d], 1);
        esrc[pos] = src[e];
        ew[pos] = w[e];
    }
}

// transpose + fp16 convert: WT[n][k] = h(W[k][n]);  W is K x N row-major
__global__ void convT_k(const float* __restrict__ W, _Float16* __restrict__ WT, int K, int N) {
    int idx = blockIdx.x * 256 + threadIdx.x;
    if (idx < K * N) {
        int k = idx / N, n = idx % N;
        WT[n * K + k] = (_Float16)W[idx];
    }
}

// flat fp32 -> fp16 convert (4-wide)
__global__ void conv4_k(const float* __restrict__ A, _Float16* __restrict__ B, int n4) {
    int i = blockIdx.x * 256 + threadIdx.x;
    if (i < n4) {
        float4 v = ((const float4*)A)[i];
        f16x4 h;
        h.x = (_Float16)v.x; h.y = (_Float16)v.y; h.z = (_Float16)v.z; h.w = (_Float16)v.w;
        ((f16x4*)B)[i] = h;
    }
}

// ---------------- SpMM (CSR, fp16 rows) + bias + relu (+ l2norm) + xsum ----------------
template <bool NORM, bool INITSUM>
__global__ void spmm_k(const _Float16* __restrict__ x, const int* __restrict__ rowptr,
                       const int* __restrict__ esrc, const float* __restrict__ ew,
                       const float* __restrict__ bias, _Float16* __restrict__ outx,
                       float* __restrict__ xsum) {
    int row = blockIdx.x * 4 + (threadIdx.x >> 6);
    int lane = threadIdx.x & 63;
    if (row >= NN) return;
    int e0 = rowptr[row], e1 = rowptr[row + 1];
    float ax = 0.f, ay = 0.f;
    for (int e = e0; e < e1; ++e) {
        int s = esrc[e];
        float w = ew[e];
        f16x2 v = ((const f16x2*)(x + (size_t)s * HID))[lane];
        ax += w * (float)v.x;
        ay += w * (float)v.y;
    }
    ax = fmaxf(ax + bias[lane * 2], 0.f);
    ay = fmaxf(ay + bias[lane * 2 + 1], 0.f);
    if (NORM) {
        float ss = ax * ax + ay * ay;
#pragma unroll
        for (int o = 32; o >= 1; o >>= 1) ss += __shfl_xor(ss, o, 64);
        float nrm = sqrtf(ss);
        float sc = 1.0f / fmaxf(nrm, 1e-12f);
        ax *= sc;
        ay *= sc;
    }
    f16x2 ho;
    ho.x = (_Float16)ax; ho.y = (_Float16)ay;
    ((f16x2*)(outx + (size_t)row * HID))[lane] = ho;
    float2* srow = (float2*)(xsum + (size_t)row * HID);
    if (INITSUM) {
        srow[lane] = make_float2(ax, ay);
    } else {
        float2 p = srow[lane];
        srow[lane] = make_float2(p.x + ax, p.y + ay);
    }
}

// ---------------- fused MLP: sacc += relu(relu(X@L1+bl1)@L2+bl2)@L3 + bl3 ----------------
// 64 rows/block, 4 waves; wave w owns a 64-col slice of both hidden layers.
// FP16IN: X is fp16 (cur); else fp32 (xsum).
template <bool FP16IN>
__global__ __launch_bounds__(256) void mlp_fused_k(
    const void* __restrict__ Xv,        // NN x 128
    const _Float16* __restrict__ L1T,   // 256 x 128 (N-major)
    const float* __restrict__ bl1,      // 256
    const _Float16* __restrict__ L2T,   // 256 x 256 (N-major)
    const float* __restrict__ bl2,      // 256
    const float* __restrict__ L3,       // 256
    const float* __restrict__ bl3,      // 1
    float* __restrict__ sacc) {
    __shared__ _Float16 Xs[64][128];
    __shared__ _Float16 H1s[64][256];
    __shared__ float Hred[4][64];
    int t = threadIdx.x;
    int w = t >> 6, l = t & 63;
    int g = l >> 4, li = l & 15;
    int rowBase = blockIdx.x * 64;

    if (FP16IN) {
        const _Float16* X = (const _Float16*)Xv;
#pragma unroll
        for (int i = 0; i < 4; ++i) {
            int idx = t + i * 256;          // 0..1023
            int r = idx >> 4, c8 = idx & 15;
            int gr = rowBase + r;
            f16x8 v = (gr < NN) ? *(const f16x8*)(X + (size_t)gr * 128 + c8 * 8)
                                : (f16x8)(_Float16)0.f;
            *(f16x8*)&Xs[r][SWZ(r, c8 * 8)] = v;
        }
    } else {
        const float* X = (const float*)Xv;
#pragma unroll
        for (int i = 0; i < 8; ++i) {
            int idx = t + i * 256;          // 0..2047
            int r = idx >> 5, c4 = idx & 31;
            int gr = rowBase + r;
            float4 v = (gr < NN) ? ((const float4*)(X + (size_t)gr * 128))[c4]
                                 : make_float4(0.f, 0.f, 0.f, 0.f);
            f16x4 u;
            u.x = (_Float16)v.x; u.y = (_Float16)v.y; u.z = (_Float16)v.z; u.w = (_Float16)v.w;
            *(f16x4*)&Xs[r][SWZ(r, c4 * 4)] = u;
        }
    }
    __syncthreads();

    int colW = w * 64;
    // GEMM1: H1 = relu(X @ L1 + bl1)
    f32x4 acc[4][4] = {};
#pragma unroll
    for (int ks = 0; ks < 4; ++ks) {
        int kb = ks * 32 + g * 8;
        f16x8 a[4];
#pragma unroll
        for (int mt = 0; mt < 4; ++mt) {
            int r = mt * 16 + li;
            a[mt] = *(const f16x8*)&Xs[r][SWZ(r, kb)];
        }
#pragma unroll
        for (int nt = 0; nt < 4; ++nt) {
            int n = colW + nt * 16 + li;
            f16x8 b = *(const f16x8*)(L1T + n * 128 + kb);
#pragma unroll
            for (int mt = 0; mt < 4; ++mt)
                acc[mt][nt] = __builtin_amdgcn_mfma_f32_16x16x32_f16(a[mt], b, acc[mt][nt], 0, 0, 0);
        }
    }
#pragma unroll
    for (int nt = 0; nt < 4; ++nt) {
        int col = colW + nt * 16 + li;
        float bb = bl1[col];
#pragma unroll
        for (int mt = 0; mt < 4; ++mt)
#pragma unroll
            for (int r4 = 0; r4 < 4; ++r4) {
                int row = mt * 16 + g * 4 + r4;
                H1s[row][SWZ(row, col)] = (_Float16)fmaxf(acc[mt][nt][r4] + bb, 0.f);
            }
    }
    __syncthreads();

    // GEMM2: H2 = relu(H1 @ L2 + bl2); fold L3 dot
    f32x4 acc2[4][4] = {};
#pragma unroll
    for (int ks = 0; ks < 8; ++ks) {
        int kb = ks * 32 + g * 8;
        f16x8 a[4];
#pragma unroll
        for (int mt = 0; mt < 4; ++mt) {
            int r = mt * 16 + li;
            a[mt] = *(const f16x8*)&H1s[r][SWZ(r, kb)];
        }
#pragma unroll
        for (int nt = 0; nt < 4; ++nt) {
            int n = colW + nt * 16 + li;
            f16x8 b = *(const f16x8*)(L2T + n * 256 + kb);
#pragma unroll
            for (int mt = 0; mt < 4; ++mt)
                acc2[mt][nt] = __builtin_amdgcn_mfma_f32_16x16x32_f16(a[mt], b, acc2[mt][nt], 0, 0, 0);
        }
    }
    float part[4][4] = {};
#pragma unroll
    for (int nt = 0; nt < 4; ++nt) {
        int col = colW + nt * 16 + li;
        float bb = bl2[col];
        float l3v = L3[col];
#pragma unroll
        for (int mt = 0; mt < 4; ++mt)
#pragma unroll
            for (int r4 = 0; r4 < 4; ++r4)
                part[mt][r4] += fmaxf(acc2[mt][nt][r4] + bb, 0.f) * l3v;
    }
#pragma unroll
    for (int mt = 0; mt < 4; ++mt)
#pragma unroll
        for (int r4 = 0; r4 < 4; ++r4) {
            float p = part[mt][r4];
            p += __shfl_xor(p, 1, 64);
            p += __shfl_xor(p, 2, 64);
            p += __shfl_xor(p, 4, 64);
            p += __shfl_xor(p, 8, 64);
            if (li == 0) Hred[w][mt * 16 + g * 4 + r4] = p;
        }
    __syncthreads();
    if (t < 64) {
        int gr = rowBase + t;
        if (gr < NN)
            sacc[gr] += Hred[0][t] + Hred[1][t] + Hred[2][t] + Hred[3][t] + bl3[0];
    }
}

// ---------------- Y[M x 128] = X[M x 128] @ W (WT fp16 N-major), fp16 out ----------------
__global__ __launch_bounds__(256) void gemm128_mfma_k(const _Float16* __restrict__ X,
                                                      const _Float16* __restrict__ WT,
                                                      _Float16* __restrict__ Y) {
    __shared__ _Float16 Xs[64][128];
    int t = threadIdx.x;
    int w = t >> 6, l = t & 63;
    int g = l >> 4, li = l & 15;
    int rowBase = blockIdx.x * 64;
#pragma unroll
    for (int i = 0; i < 4; ++i) {
        int idx = t + i * 256;
        int r = idx >> 4, c8 = idx & 15;
        int gr = rowBase + r;
        f16x8 v = (gr < NN) ? *(const f16x8*)(X + (size_t)gr * 128 + c8 * 8)
                            : (f16x8)(_Float16)0.f;
        *(f16x8*)&Xs[r][SWZ(r, c8 * 8)] = v;
    }
    __syncthreads();
    int colW = w * 32;
    f32x4 acc[4][2] = {};
#pragma unroll
    for (int ks = 0; ks < 4; ++ks) {
        int kb = ks * 32 + g * 8;
        f16x8 a[4];
#pragma unroll
        for (int mt = 0; mt < 4; ++mt) {
            int r = mt * 16 + li;
            a[mt] = *(const f16x8*)&Xs[r][SWZ(r, kb)];
        }
#pragma unroll
        for (int nt = 0; nt < 2; ++nt) {
            int n = colW + nt * 16 + li;
            f16x8 b = *(const f16x8*)(WT + n * 128 + kb);
#pragma unroll
            for (int mt = 0; mt < 4; ++mt)
                acc[mt][nt] = __builtin_amdgcn_mfma_f32_16x16x32_f16(a[mt], b, acc[mt][nt], 0, 0, 0);
        }
    }
#pragma unroll
    for (int mt = 0; mt < 4; ++mt)
#pragma unroll
        for (int nt = 0; nt < 2; ++nt)
#pragma unroll
            for (int r4 = 0; r4 < 4; ++r4) {
                int gr = rowBase + mt * 16 + g * 4 + r4;
                if (gr < NN)
                    Y[(size_t)gr * 128 + colW + nt * 16 + li] = (_Float16)acc[mt][nt][r4];
            }
}

__global__ void score_store_k(const float* __restrict__ sacc, float* __restrict__ dst) {
    int i = blockIdx.x * 256 + threadIdx.x;
    if (i < NN) dst[i] = sacc[i] * (1.f / 7.f);
}

__global__ void final_mul_k(const float* __restrict__ sacc, const float* __restrict__ score1,
                            float* __restrict__ out) {
    int i = blockIdx.x * 256 + threadIdx.x;
    if (i < NN) out[i] = score1[i] * (sacc[i] * (1.f / 7.f));
}

// ---------------- host orchestration ----------------
extern "C" void kernel_launch(void* const* d_in, const int* in_sizes, int n_in,
                              void* d_out, int out_size, void* d_ws, size_t ws_size,
                              hipStream_t stream) {
    const int* asrc[2] = {(const int*)d_in[0], (const int*)d_in[3]};
    const int* adst[2] = {(const int*)d_in[1], (const int*)d_in[4]};
    const float* aw[2] = {(const float*)d_in[2], (const float*)d_in[5]};
    const float* W1 = (const float*)d_in[6];
    const float* b1 = (const float*)d_in[7];
    const float* Wk[5] = {(const float*)d_in[8], (const float*)d_in[10], (const float*)d_in[12],
                          (const float*)d_in[14], (const float*)d_in[16]};
    const float* bk[5] = {(const float*)d_in[9], (const float*)d_in[11], (const float*)d_in[13],
                          (const float*)d_in[15], (const float*)d_in[17]};
    const float* L1 = (const float*)d_in[18];
    const float* bl1 = (const float*)d_in[19];
    const float* L2 = (const float*)d_in[20];
    const float* bl2 = (const float*)d_in[21];
    const float* L3 = (const float*)d_in[22];
    const float* bl3 = (const float*)d_in[23];
    float* out = (float*)d_out;

    // workspace layout (fp16 weight/activation buffers first, 16B aligned)
    char* w8 = (char*)d_ws;
    _Float16* L1T = (_Float16*)w8;                         // 256*128*2 = 64 KB
    _Float16* L2T = (_Float16*)(w8 + 65536);               // 256*256*2 = 128 KB
    _Float16* WkT = (_Float16*)(w8 + 65536 + 131072);      // 5*128*128*2 = 160 KB
    _Float16* W1h = (_Float16*)(w8 + 65536 + 131072 + 163840);  // NN*128*2
    _Float16* cur = W1h + (size_t)NN * HID;                // NN*128 fp16
    _Float16* tmp = cur + (size_t)NN * HID;                // NN*128 fp16
    float* xsum = (float*)(tmp + (size_t)NN * HID);        // NN*128 fp32
    float* sacc = xsum + (size_t)NN * HID;                 // NN
    float* score1 = sacc + NN;                             // NN
    int* rowptr = (int*)(score1 + NN);                     // NN+1
    int* cursor = rowptr + (NN + 1);                       // NN
    int* esrc = cursor + NN;                               // NE
    float* ew = (float*)(esrc + NE);                       // NE

    const int GE = (NE + 255) / 256;
    const int GN = (NN + 255) / 256;
    const int GS = (NN + 3) / 4;
    const int GM = (NN + 63) / 64;  // 1563

    // ---- one-time weight conversion ----
    convT_k<<<(128 * 256 + 255) / 256, 256, 0, stream>>>(L1, L1T, 128, 256);
    convT_k<<<(256 * 256 + 255) / 256, 256, 0, stream>>>(L2, L2T, 256, 256);
    for (int l = 0; l < 5; ++l)
        convT_k<<<(128 * 128 + 255) / 256, 256, 0, stream>>>(Wk[l], WkT + (size_t)l * 16384, 128, 128);
    conv4_k<<<(NN * HID / 4 + 255) / 256, 256, 0, stream>>>(W1, W1h, NN * HID / 4);

    for (int br = 0; br < 2; ++br) {
        // ---- build CSR ----
        zero_k<<<GN, 256, 0, stream>>>(rowptr, NN + 1);
        hist_k<<<GE, 256, 0, stream>>>(adst[br], rowptr);
        scan_k<<<1, 1024, 0, stream>>>(rowptr, NN);
        copyi_k<<<GN, 256, 0, stream>>>(rowptr, cursor, NN);
        scatter_k<<<GE, 256, 0, stream>>>(asrc[br], adst[br], aw[br], cursor, esrc, ew);

        zero_k<<<GN, 256, 0, stream>>>((int*)sacc, NN);

        // ---- layer 1: x1 = norm(relu(spmm(W1)+b1)) ----
        spmm_k<true, true><<<GS, 256, 0, stream>>>(W1h, rowptr, esrc, ew, b1, cur, xsum);
        mlp_fused_k<true><<<GM, 256, 0, stream>>>(cur, L1T, bl1, L2T, bl2, L3, bl3, sacc);

        // ---- layers 2..6 ----
        for (int l = 0; l < 5; ++l) {
            gemm128_mfma_k<<<GM, 256, 0, stream>>>(cur, WkT + (size_t)l * 16384, tmp);
            if (l < 4)
                spmm_k<true, false><<<GS, 256, 0, stream>>>(tmp, rowptr, esrc, ew, bk[l], cur, xsum);
            else
                spmm_k<false, false><<<GS, 256, 0, stream>>>(tmp, rowptr, esrc, ew, bk[l], cur, xsum);
            mlp_fused_k<true><<<GM, 256, 0, stream>>>(cur, L1T, bl1, L2T, bl2, L3, bl3, sacc);
        }

        // ---- mlp(x7 = xsum, fp32 input) ----
        mlp_fused_k<false><<<GM, 256, 0, stream>>>(xsum, L1T, bl1, L2T, bl2, L3, bl3, sacc);

        if (br == 0)
            score_store_k<<<GN, 256, 0, stream>>>(sacc, score1);
        else
            final_mul_k<<<GN, 256, 0, stream>>>(sacc, score1, out);
    }
}

// Round 4
// 3248.000 us; speedup vs baseline: 3.0656x; 1.6280x over previous
//
#include <hip/hip_runtime.h>

#define NN 100000
#define NE 3200000
#define HID 128

typedef __attribute__((ext_vector_type(8))) _Float16 f16x8;
typedef __attribute__((ext_vector_type(4))) _Float16 f16x4;
typedef __attribute__((ext_vector_type(2))) _Float16 f16x2;
typedef __attribute__((ext_vector_type(4))) float f32x4;

// swizzle in element units: XOR elem bits 3..5 with row bits 0..2
#define SWZ(row, k) ((k) ^ (((row) & 7) << 3))

// ---------------- small utility kernels ----------------
__global__ void zero_k(int* p, int n) {
    int i = blockIdx.x * 256 + threadIdx.x;
    if (i < n) p[i] = 0;
}

__global__ void copyi_k(const int* __restrict__ a, int* __restrict__ b, int n) {
    int i = blockIdx.x * 256 + threadIdx.x;
    if (i < n) b[i] = a[i];
}

__global__ void hist_k(const int* __restrict__ dst, int* __restrict__ cnt) {
    int e = blockIdx.x * 256 + threadIdx.x;
    if (e < NE) atomicAdd(&cnt[dst[e]], 1);
}

// single-block exclusive scan of rowptr[0..n), writes rowptr[n]=total
__global__ void scan_k(int* __restrict__ rowptr, int n) {
    __shared__ int wsum[16];
    int tid = threadIdx.x;
    int lane = tid & 63, wid = tid >> 6;
    int carry = 0;
    for (int base = 0; base < n; base += 1024) {
        int idx = base + tid;
        int v = (idx < n) ? rowptr[idx] : 0;
        int s = v;
#pragma unroll
        for (int o = 1; o < 64; o <<= 1) {
            int t = __shfl_up(s, o, 64);
            if (lane >= o) s += t;
        }
        if (lane == 63) wsum[wid] = s;
        __syncthreads();
        if (wid == 0) {
            int ws = (lane < 16) ? wsum[lane] : 0;
#pragma unroll
            for (int o = 1; o < 16; o <<= 1) {
                int t = __shfl_up(ws, o, 64);
                if (lane >= o) ws += t;
            }
            if (lane < 16) wsum[lane] = ws;
        }
        __syncthreads();
        int woff = (wid == 0) ? 0 : wsum[wid - 1];
        int excl = carry + woff + s - v;
        if (idx < n) rowptr[idx] = excl;
        carry += wsum[15];
        __syncthreads();
    }
    if (tid == 0) rowptr[n] = carry;
}

__global__ void scatter_k(const int* __restrict__ src, const int* __restrict__ dst,
                          const float* __restrict__ w, int* __restrict__ cursor,
                          int* __restrict__ esrc, float* __restrict__ ew) {
    int e = blockIdx.x * 256 + threadIdx.x;
    if (e < NE) {
        int d = dst[e];
        int pos = atomicAdd(&cursor[d], 1);
        esrc[pos] = src[e];
        ew[pos] = w[e];
    }
}

// transpose + fp16 convert: WT[n][k] = h(W[k][n]);  W is K x N row-major
__global__ void convT_k(const float* __restrict__ W, _Float16* __restrict__ WT, int K, int N) {
    int idx = blockIdx.x * 256 + threadIdx.x;
    if (idx < K * N) {
        int k = idx / N, n = idx % N;
        WT[n * K + k] = (_Float16)W[idx];
    }
}

// flat fp32 -> fp16 convert (4-wide)
__global__ void conv4_k(const float* __restrict__ A, _Float16* __restrict__ B, int n4) {
    int i = blockIdx.x * 256 + threadIdx.x;
    if (i < n4) {
        float4 v = ((const float4*)A)[i];
        f16x4 h;
        h.x = (_Float16)v.x; h.y = (_Float16)v.y; h.z = (_Float16)v.z; h.w = (_Float16)v.w;
        ((f16x4*)B)[i] = h;
    }
}

// ---------------- SpMM (CSR, fp16 rows) + bias + relu (+ l2norm) + xsum ----------------
// one wave per dst row; 4 quarter-waves each handle a different edge;
// lane li (0..15) covers cols li*8..li*8+7 with one f16x8 (16B) load.
template <bool NORM, bool INITSUM>
__global__ void spmm_k(const _Float16* __restrict__ x, const int* __restrict__ rowptr,
                       const int* __restrict__ esrc, const float* __restrict__ ew,
                       const float* __restrict__ bias, _Float16* __restrict__ outx,
                       float* __restrict__ xsum) {
    int row = blockIdx.x * 4 + (threadIdx.x >> 6);
    int l = threadIdx.x & 63;
    int q = l >> 4, li = l & 15;
    if (row >= NN) return;
    int e0 = rowptr[row], e1 = rowptr[row + 1];
    float acc[8] = {};
#pragma unroll 2
    for (int e = e0 + q; e < e1; e += 4) {
        int s = esrc[e];
        float w = ew[e];
        f16x8 v = *(const f16x8*)(x + (size_t)s * HID + li * 8);
#pragma unroll
        for (int j = 0; j < 8; ++j) acc[j] += w * (float)v[j];
    }
    // fold quarter-waves: every lane ends with the full sum for its 8 cols
#pragma unroll
    for (int j = 0; j < 8; ++j) {
        acc[j] += __shfl_xor(acc[j], 16, 64);
        acc[j] += __shfl_xor(acc[j], 32, 64);
    }
    const float4* bp = (const float4*)(bias + li * 8);
    float4 b0 = bp[0], b1 = bp[1];
    acc[0] = fmaxf(acc[0] + b0.x, 0.f); acc[1] = fmaxf(acc[1] + b0.y, 0.f);
    acc[2] = fmaxf(acc[2] + b0.z, 0.f); acc[3] = fmaxf(acc[3] + b0.w, 0.f);
    acc[4] = fmaxf(acc[4] + b1.x, 0.f); acc[5] = fmaxf(acc[5] + b1.y, 0.f);
    acc[6] = fmaxf(acc[6] + b1.z, 0.f); acc[7] = fmaxf(acc[7] + b1.w, 0.f);
    if (NORM) {
        float ss = 0.f;
#pragma unroll
        for (int j = 0; j < 8; ++j) ss += acc[j] * acc[j];
        ss += __shfl_xor(ss, 1, 64);
        ss += __shfl_xor(ss, 2, 64);
        ss += __shfl_xor(ss, 4, 64);
        ss += __shfl_xor(ss, 8, 64);
        float sc = 1.0f / fmaxf(sqrtf(ss), 1e-12f);
#pragma unroll
        for (int j = 0; j < 8; ++j) acc[j] *= sc;
    }
    if (q == 0) {  // fp16 activation row
        f16x8 ho;
#pragma unroll
        for (int j = 0; j < 8; ++j) ho[j] = (_Float16)acc[j];
        *(f16x8*)(outx + (size_t)row * HID + li * 8) = ho;
    } else if (q == 1) {  // fp32 xsum row
        f32x4* sp = (f32x4*)(xsum + (size_t)row * HID + li * 8);
        f32x4 s0, s1;
        s0[0] = acc[0]; s0[1] = acc[1]; s0[2] = acc[2]; s0[3] = acc[3];
        s1[0] = acc[4]; s1[1] = acc[5]; s1[2] = acc[6]; s1[3] = acc[7];
        if (INITSUM) {
            sp[0] = s0; sp[1] = s1;
        } else {
            f32x4 p0 = sp[0], p1 = sp[1];
#pragma unroll
            for (int j = 0; j < 4; ++j) { p0[j] += s0[j]; p1[j] += s1[j]; }
            sp[0] = p0; sp[1] = p1;
        }
    }
}

// ---------------- fused MLP: sacc += relu(relu(X@L1+bl1)@L2+bl2)@L3 + bl3 ----------------
// 64 rows/block, 4 waves; wave w owns a 64-col slice of both hidden layers.
// FP16IN: X is fp16 (cur); else fp32 (xsum).
template <bool FP16IN>
__global__ __launch_bounds__(256) void mlp_fused_k(
    const void* __restrict__ Xv,        // NN x 128
    const _Float16* __restrict__ L1T,   // 256 x 128 (N-major)
    const float* __restrict__ bl1,      // 256
    const _Float16* __restrict__ L2T,   // 256 x 256 (N-major)
    const float* __restrict__ bl2,      // 256
    const float* __restrict__ L3,       // 256
    const float* __restrict__ bl3,      // 1
    float* __restrict__ sacc) {
    __shared__ _Float16 Xs[64][128];
    __shared__ _Float16 H1s[64][256];
    __shared__ float Hred[4][64];
    int t = threadIdx.x;
    int w = t >> 6, l = t & 63;
    int g = l >> 4, li = l & 15;
    int rowBase = blockIdx.x * 64;

    if (FP16IN) {
        const _Float16* X = (const _Float16*)Xv;
#pragma unroll
        for (int i = 0; i < 4; ++i) {
            int idx = t + i * 256;          // 0..1023
            int r = idx >> 4, c8 = idx & 15;
            int gr = rowBase + r;
            f16x8 v = (gr < NN) ? *(const f16x8*)(X + (size_t)gr * 128 + c8 * 8)
                                : (f16x8)(_Float16)0.f;
            *(f16x8*)&Xs[r][SWZ(r, c8 * 8)] = v;
        }
    } else {
        const float* X = (const float*)Xv;
#pragma unroll
        for (int i = 0; i < 8; ++i) {
            int idx = t + i * 256;          // 0..2047
            int r = idx >> 5, c4 = idx & 31;
            int gr = rowBase + r;
            float4 v = (gr < NN) ? ((const float4*)(X + (size_t)gr * 128))[c4]
                                 : make_float4(0.f, 0.f, 0.f, 0.f);
            f16x4 u;
            u.x = (_Float16)v.x; u.y = (_Float16)v.y; u.z = (_Float16)v.z; u.w = (_Float16)v.w;
            *(f16x4*)&Xs[r][SWZ(r, c4 * 4)] = u;
        }
    }
    __syncthreads();

    int colW = w * 64;
    // GEMM1: H1 = relu(X @ L1 + bl1)
    f32x4 acc[4][4] = {};
#pragma unroll
    for (int ks = 0; ks < 4; ++ks) {
        int kb = ks * 32 + g * 8;
        f16x8 a[4];
#pragma unroll
        for (int mt = 0; mt < 4; ++mt) {
            int r = mt * 16 + li;
            a[mt] = *(const f16x8*)&Xs[r][SWZ(r, kb)];
        }
#pragma unroll
        for (int nt = 0; nt < 4; ++nt) {
            int n = colW + nt * 16 + li;
            f16x8 b = *(const f16x8*)(L1T + n * 128 + kb);
#pragma unroll
            for (int mt = 0; mt < 4; ++mt)
                acc[mt][nt] = __builtin_amdgcn_mfma_f32_16x16x32_f16(a[mt], b, acc[mt][nt], 0, 0, 0);
        }
    }
#pragma unroll
    for (int nt = 0; nt < 4; ++nt) {
        int col = colW + nt * 16 + li;
        float bb = bl1[col];
#pragma unroll
        for (int mt = 0; mt < 4; ++mt)
#pragma unroll
            for (int r4 = 0; r4 < 4; ++r4) {
                int row = mt * 16 + g * 4 + r4;
                H1s[row][SWZ(row, col)] = (_Float16)fmaxf(acc[mt][nt][r4] + bb, 0.f);
            }
    }
    __syncthreads();

    // GEMM2: H2 = relu(H1 @ L2 + bl2); fold L3 dot
    f32x4 acc2[4][4] = {};
#pragma unroll
    for (int ks = 0; ks < 8; ++ks) {
        int kb = ks * 32 + g * 8;
        f16x8 a[4];
#pragma unroll
        for (int mt = 0; mt < 4; ++mt) {
            int r = mt * 16 + li;
            a[mt] = *(const f16x8*)&H1s[r][SWZ(r, kb)];
        }
#pragma unroll
        for (int nt = 0; nt < 4; ++nt) {
            int n = colW + nt * 16 + li;
            f16x8 b = *(const f16x8*)(L2T + n * 256 + kb);
#pragma unroll
            for (int mt = 0; mt < 4; ++mt)
                acc2[mt][nt] = __builtin_amdgcn_mfma_f32_16x16x32_f16(a[mt], b, acc2[mt][nt], 0, 0, 0);
        }
    }
    float part[4][4] = {};
#pragma unroll
    for (int nt = 0; nt < 4; ++nt) {
        int col = colW + nt * 16 + li;
        float bb = bl2[col];
        float l3v = L3[col];
#pragma unroll
        for (int mt = 0; mt < 4; ++mt)
#pragma unroll
            for (int r4 = 0; r4 < 4; ++r4)
                part[mt][r4] += fmaxf(acc2[mt][nt][r4] + bb, 0.f) * l3v;
    }
#pragma unroll
    for (int mt = 0; mt < 4; ++mt)
#pragma unroll
        for (int r4 = 0; r4 < 4; ++r4) {
            float p = part[mt][r4];
            p += __shfl_xor(p, 1, 64);
            p += __shfl_xor(p, 2, 64);
            p += __shfl_xor(p, 4, 64);
            p += __shfl_xor(p, 8, 64);
            if (li == 0) Hred[w][mt * 16 + g * 4 + r4] = p;
        }
    __syncthreads();
    if (t < 64) {
        int gr = rowBase + t;
        if (gr < NN)
            sacc[gr] += Hred[0][t] + Hred[1][t] + Hred[2][t] + Hred[3][t] + bl3[0];
    }
}

// ---------------- Y[M x 128] = X[M x 128] @ W (WT fp16 N-major), fp16 out ----------------
__global__ __launch_bounds__(256) void gemm128_mfma_k(const _Float16* __restrict__ X,
                                                      const _Float16* __restrict__ WT,
                                                      _Float16* __restrict__ Y) {
    __shared__ _Float16 Xs[64][128];
    int t = threadIdx.x;
    int w = t >> 6, l = t & 63;
    int g = l >> 4, li = l & 15;
    int rowBase = blockIdx.x * 64;
#pragma unroll
    for (int i = 0; i < 4; ++i) {
        int idx = t + i * 256;
        int r = idx >> 4, c8 = idx & 15;
        int gr = rowBase + r;
        f16x8 v = (gr < NN) ? *(const f16x8*)(X + (size_t)gr * 128 + c8 * 8)
                            : (f16x8)(_Float16)0.f;
        *(f16x8*)&Xs[r][SWZ(r, c8 * 8)] = v;
    }
    __syncthreads();
    int colW = w * 32;
    f32x4 acc[4][2] = {};
#pragma unroll
    for (int ks = 0; ks < 4; ++ks) {
        int kb = ks * 32 + g * 8;
        f16x8 a[4];
#pragma unroll
        for (int mt = 0; mt < 4; ++mt) {
            int r = mt * 16 + li;
            a[mt] = *(const f16x8*)&Xs[r][SWZ(r, kb)];
        }
#pragma unroll
        for (int nt = 0; nt < 2; ++nt) {
            int n = colW + nt * 16 + li;
            f16x8 b = *(const f16x8*)(WT + n * 128 + kb);
#pragma unroll
            for (int mt = 0; mt < 4; ++mt)
                acc[mt][nt] = __builtin_amdgcn_mfma_f32_16x16x32_f16(a[mt], b, acc[mt][nt], 0, 0, 0);
        }
    }
#pragma unroll
    for (int mt = 0; mt < 4; ++mt)
#pragma unroll
        for (int nt = 0; nt < 2; ++nt)
#pragma unroll
            for (int r4 = 0; r4 < 4; ++r4) {
                int gr = rowBase + mt * 16 + g * 4 + r4;
                if (gr < NN)
                    Y[(size_t)gr * 128 + colW + nt * 16 + li] = (_Float16)acc[mt][nt][r4];
            }
}

__global__ void score_store_k(const float* __restrict__ sacc, float* __restrict__ dst) {
    int i = blockIdx.x * 256 + threadIdx.x;
    if (i < NN) dst[i] = sacc[i] * (1.f / 7.f);
}

__global__ void final_mul_k(const float* __restrict__ sacc, const float* __restrict__ score1,
                            float* __restrict__ out) {
    int i = blockIdx.x * 256 + threadIdx.x;
    if (i < NN) out[i] = score1[i] * (sacc[i] * (1.f / 7.f));
}

// ---------------- host orchestration ----------------
extern "C" void kernel_launch(void* const* d_in, const int* in_sizes, int n_in,
                              void* d_out, int out_size, void* d_ws, size_t ws_size,
                              hipStream_t stream) {
    const int* asrc[2] = {(const int*)d_in[0], (const int*)d_in[3]};
    const int* adst[2] = {(const int*)d_in[1], (const int*)d_in[4]};
    const float* aw[2] = {(const float*)d_in[2], (const float*)d_in[5]};
    const float* W1 = (const float*)d_in[6];
    const float* b1 = (const float*)d_in[7];
    const float* Wk[5] = {(const float*)d_in[8], (const float*)d_in[10], (const float*)d_in[12],
                          (const float*)d_in[14], (const float*)d_in[16]};
    const float* bk[5] = {(const float*)d_in[9], (const float*)d_in[11], (const float*)d_in[13],
                          (const float*)d_in[15], (const float*)d_in[17]};
    const float* L1 = (const float*)d_in[18];
    const float* bl1 = (const float*)d_in[19];
    const float* L2 = (const float*)d_in[20];
    const float* bl2 = (const float*)d_in[21];
    const float* L3 = (const float*)d_in[22];
    const float* bl3 = (const float*)d_in[23];
    float* out = (float*)d_out;

    // workspace layout (fp16 weight/activation buffers first, 16B aligned)
    char* w8 = (char*)d_ws;
    _Float16* L1T = (_Float16*)w8;                         // 256*128*2 = 64 KB
    _Float16* L2T = (_Float16*)(w8 + 65536);               // 256*256*2 = 128 KB
    _Float16* WkT = (_Float16*)(w8 + 65536 + 131072);      // 5*128*128*2 = 160 KB
    _Float16* W1h = (_Float16*)(w8 + 65536 + 131072 + 163840);  // NN*128*2
    _Float16* cur = W1h + (size_t)NN * HID;                // NN*128 fp16
    _Float16* tmp = cur + (size_t)NN * HID;                // NN*128 fp16
    float* xsum = (float*)(tmp + (size_t)NN * HID);        // NN*128 fp32
    float* sacc = xsum + (size_t)NN * HID;                 // NN
    float* score1 = sacc + NN;                             // NN
    int* rowptr = (int*)(score1 + NN);                     // NN+1
    int* cursor = rowptr + (NN + 1);                       // NN
    int* esrc = cursor + NN;                               // NE
    float* ew = (float*)(esrc + NE);                       // NE

    const int GE = (NE + 255) / 256;
    const int GN = (NN + 255) / 256;
    const int GS = (NN + 3) / 4;
    const int GM = (NN + 63) / 64;  // 1563

    // ---- one-time weight conversion ----
    convT_k<<<(128 * 256 + 255) / 256, 256, 0, stream>>>(L1, L1T, 128, 256);
    convT_k<<<(256 * 256 + 255) / 256, 256, 0, stream>>>(L2, L2T, 256, 256);
    for (int l = 0; l < 5; ++l)
        convT_k<<<(128 * 128 + 255) / 256, 256, 0, stream>>>(Wk[l], WkT + (size_t)l * 16384, 128, 128);
    conv4_k<<<(NN * HID / 4 + 255) / 256, 256, 0, stream>>>(W1, W1h, NN * HID / 4);

    for (int br = 0; br < 2; ++br) {
        // ---- build CSR ----
        zero_k<<<GN, 256, 0, stream>>>(rowptr, NN + 1);
        hist_k<<<GE, 256, 0, stream>>>(adst[br], rowptr);
        scan_k<<<1, 1024, 0, stream>>>(rowptr, NN);
        copyi_k<<<GN, 256, 0, stream>>>(rowptr, cursor, NN);
        scatter_k<<<GE, 256, 0, stream>>>(asrc[br], adst[br], aw[br], cursor, esrc, ew);

        zero_k<<<GN, 256, 0, stream>>>((int*)sacc, NN);

        // ---- layer 1: x1 = norm(relu(spmm(W1)+b1)) ----
        spmm_k<true, true><<<GS, 256, 0, stream>>>(W1h, rowptr, esrc, ew, b1, cur, xsum);
        mlp_fused_k<true><<<GM, 256, 0, stream>>>(cur, L1T, bl1, L2T, bl2, L3, bl3, sacc);

        // ---- layers 2..6 ----
        for (int l = 0; l < 5; ++l) {
            gemm128_mfma_k<<<GM, 256, 0, stream>>>(cur, WkT + (size_t)l * 16384, tmp);
            if (l < 4)
                spmm_k<true, false><<<GS, 256, 0, stream>>>(tmp, rowptr, esrc, ew, bk[l], cur, xsum);
            else
                spmm_k<false, false><<<GS, 256, 0, stream>>>(tmp, rowptr, esrc, ew, bk[l], cur, xsum);
            mlp_fused_k<true><<<GM, 256, 0, stream>>>(cur, L1T, bl1, L2T, bl2, L3, bl3, sacc);
        }

        // ---- mlp(x7 = xsum, fp32 input) ----
        mlp_fused_k<false><<<GM, 256, 0, stream>>>(xsum, L1T, bl1, L2T, bl2, L3, bl3, sacc);

        if (br == 0)
            score_store_k<<<GN, 256, 0, stream>>>(sacc, score1);
        else
            final_mul_k<<<GN, 256, 0, stream>>>(sacc, score1, out);
    }
}

// Round 5
// 2874.164 us; speedup vs baseline: 3.4643x; 1.1301x over previous
//
#include <hip/hip_runtime.h>

#define NN 100000
#define NE 3200000
#define HID 128
#define NNH ((size_t)NN * HID)

typedef __attribute__((ext_vector_type(8))) _Float16 f16x8;
typedef __attribute__((ext_vector_type(4))) _Float16 f16x4;
typedef __attribute__((ext_vector_type(4))) float f32x4;

// swizzle in element units: XOR elem bits 3..5 with row bits 0..2
#define SWZ(row, k) ((k) ^ (((row) & 7) << 3))

// ---------------- small utility kernels ----------------
__global__ void zero_k(int* p, int n) {
    int i = blockIdx.x * 256 + threadIdx.x;
    if (i < n) p[i] = 0;
}

__global__ void hist_k(const int* __restrict__ dst, int* __restrict__ cnt) {
    int e = blockIdx.x * 256 + threadIdx.x;
    if (e < NE) atomicAdd(&cnt[dst[e]], 1);
}

// ---- multi-block exclusive scan of rowptr[0..n) ----
// A: per-block local exclusive scan + block sums
__global__ __launch_bounds__(1024) void scanA_k(int* __restrict__ rowptr, int* __restrict__ bsum, int n) {
    __shared__ int wsum[16];
    int tid = threadIdx.x;
    int lane = tid & 63, wid = tid >> 6;
    int idx = blockIdx.x * 1024 + tid;
    int v = (idx < n) ? rowptr[idx] : 0;
    int s = v;
#pragma unroll
    for (int o = 1; o < 64; o <<= 1) {
        int t = __shfl_up(s, o, 64);
        if (lane >= o) s += t;
    }
    if (lane == 63) wsum[wid] = s;
    __syncthreads();
    if (wid == 0) {
        int ws = (lane < 16) ? wsum[lane] : 0;
#pragma unroll
        for (int o = 1; o < 16; o <<= 1) {
            int t = __shfl_up(ws, o, 64);
            if (lane >= o) ws += t;
        }
        if (lane < 16) wsum[lane] = ws;
    }
    __syncthreads();
    int woff = (wid == 0) ? 0 : wsum[wid - 1];
    if (idx < n) rowptr[idx] = woff + s - v;
    if (tid == 0) bsum[blockIdx.x] = wsum[15];
}

// B: serial scan of block sums (nb <= 128), writes rowptr[n] = total
__global__ void scanB_k(int* __restrict__ bsum, int* __restrict__ rowptr, int nb, int n) {
    if (threadIdx.x == 0) {
        int run = 0;
        for (int i = 0; i < nb; ++i) {
            int t = bsum[i];
            bsum[i] = run;
            run += t;
        }
        rowptr[n] = run;
    }
}

// C: add block offsets; also produce cursor copy
__global__ void scanC_k(int* __restrict__ rowptr, int* __restrict__ cursor,
                        const int* __restrict__ bsum, int n) {
    int idx = blockIdx.x * 256 + threadIdx.x;
    if (idx < n) {
        int v = rowptr[idx] + bsum[idx >> 10];
        rowptr[idx] = v;
        cursor[idx] = v;
    }
}

// packed scatter: one 8B record per edge
__global__ void scatter_k(const int* __restrict__ src, const int* __restrict__ dst,
                          const float* __restrict__ w, int* __restrict__ cursor,
                          int2* __restrict__ ep) {
    int e = blockIdx.x * 256 + threadIdx.x;
    if (e < NE) {
        int d = dst[e];
        int pos = atomicAdd(&cursor[d], 1);
        ep[pos] = make_int2(src[e], __float_as_int(w[e]));
    }
}

// transpose + fp16 convert: WT[n][k] = h(W[k][n]);  W is K x N row-major
__global__ void convT_k(const float* __restrict__ W, _Float16* __restrict__ WT, int K, int N) {
    int idx = blockIdx.x * 256 + threadIdx.x;
    if (idx < K * N) {
        int k = idx / N, n = idx % N;
        WT[n * K + k] = (_Float16)W[idx];
    }
}

// flat fp32 -> fp16 convert (4-wide)
__global__ void conv4_k(const float* __restrict__ A, _Float16* __restrict__ B, int n4) {
    int i = blockIdx.x * 256 + threadIdx.x;
    if (i < n4) {
        float4 v = ((const float4*)A)[i];
        f16x4 h;
        h.x = (_Float16)v.x; h.y = (_Float16)v.y; h.z = (_Float16)v.z; h.w = (_Float16)v.w;
        ((f16x4*)B)[i] = h;
    }
}

// ---------------- SpMM (CSR packed, fp16 rows) + bias + relu (+ l2norm) ----------------
// one wave per dst row; 4 quarter-waves over edges; lane li: cols li*8..li*8+7 (16B load)
template <bool NORM>
__global__ void spmm_k(const _Float16* __restrict__ x, const int* __restrict__ rowptr,
                       const int2* __restrict__ ep, const float* __restrict__ bias,
                       _Float16* __restrict__ outx) {
    int row = blockIdx.x * 4 + (threadIdx.x >> 6);
    int l = threadIdx.x & 63;
    int q = l >> 4, li = l & 15;
    if (row >= NN) return;
    int e0 = rowptr[row], e1 = rowptr[row + 1];
    float acc[8] = {};
#pragma unroll 4
    for (int e = e0 + q; e < e1; e += 4) {
        int2 r = ep[e];
        float w = __int_as_float(r.y);
        f16x8 v = *(const f16x8*)(x + (size_t)r.x * HID + li * 8);
#pragma unroll
        for (int j = 0; j < 8; ++j) acc[j] += w * (float)v[j];
    }
#pragma unroll
    for (int j = 0; j < 8; ++j) {
        acc[j] += __shfl_xor(acc[j], 16, 64);
        acc[j] += __shfl_xor(acc[j], 32, 64);
    }
    const float4* bp = (const float4*)(bias + li * 8);
    float4 b0 = bp[0], b1 = bp[1];
    acc[0] = fmaxf(acc[0] + b0.x, 0.f); acc[1] = fmaxf(acc[1] + b0.y, 0.f);
    acc[2] = fmaxf(acc[2] + b0.z, 0.f); acc[3] = fmaxf(acc[3] + b0.w, 0.f);
    acc[4] = fmaxf(acc[4] + b1.x, 0.f); acc[5] = fmaxf(acc[5] + b1.y, 0.f);
    acc[6] = fmaxf(acc[6] + b1.z, 0.f); acc[7] = fmaxf(acc[7] + b1.w, 0.f);
    if (NORM) {
        float ss = 0.f;
#pragma unroll
        for (int j = 0; j < 8; ++j) ss += acc[j] * acc[j];
        ss += __shfl_xor(ss, 1, 64);
        ss += __shfl_xor(ss, 2, 64);
        ss += __shfl_xor(ss, 4, 64);
        ss += __shfl_xor(ss, 8, 64);
        float sc = 1.0f / fmaxf(sqrtf(ss), 1e-12f);
#pragma unroll
        for (int j = 0; j < 8; ++j) acc[j] *= sc;
    }
    if (q == 0) {
        f16x8 ho;
#pragma unroll
        for (int j = 0; j < 8; ++j) ho[j] = (_Float16)acc[j];
        *(f16x8*)(outx + (size_t)row * HID + li * 8) = ho;
    }
}

// ---------------- fused MLP: sacc += relu(relu(X@L1+bl1)@L2+bl2)@L3 + bl3 ----------------
// SUM6: X = sum of 6 fp16 buffers (x7 path); else single fp16 buffer.
template <bool SUM6>
__global__ __launch_bounds__(256) void mlp_fused_k(
    const _Float16* __restrict__ X,     // NN x 128 (or 6 stacked: l*NNH)
    const _Float16* __restrict__ L1T,   // 256 x 128 (N-major)
    const float* __restrict__ bl1,      // 256
    const _Float16* __restrict__ L2T,   // 256 x 256 (N-major)
    const float* __restrict__ bl2,      // 256
    const float* __restrict__ L3,       // 256
    const float* __restrict__ bl3,      // 1
    float* __restrict__ sacc) {
    __shared__ _Float16 Xs[64][128];
    __shared__ _Float16 H1s[64][256];
    __shared__ float Hred[4][64];
    int t = threadIdx.x;
    int w = t >> 6, l = t & 63;
    int g = l >> 4, li = l & 15;
    int rowBase = blockIdx.x * 64;

#pragma unroll
    for (int i = 0; i < 4; ++i) {
        int idx = t + i * 256;          // 0..1023
        int r = idx >> 4, c8 = idx & 15;
        int gr = rowBase + r;
        if (SUM6) {
            float s[8] = {};
            if (gr < NN) {
#pragma unroll
                for (int l6 = 0; l6 < 6; ++l6) {
                    f16x8 v = *(const f16x8*)(X + (size_t)l6 * NNH + (size_t)gr * HID + c8 * 8);
#pragma unroll
                    for (int j = 0; j < 8; ++j) s[j] += (float)v[j];
                }
            }
            f16x8 hv;
#pragma unroll
            for (int j = 0; j < 8; ++j) hv[j] = (_Float16)s[j];
            *(f16x8*)&Xs[r][SWZ(r, c8 * 8)] = hv;
        } else {
            f16x8 v = (gr < NN) ? *(const f16x8*)(X + (size_t)gr * HID + c8 * 8)
                                : (f16x8)(_Float16)0.f;
            *(f16x8*)&Xs[r][SWZ(r, c8 * 8)] = v;
        }
    }
    __syncthreads();

    int colW = w * 64;
    // GEMM1: H1 = relu(X @ L1 + bl1)
    f32x4 acc[4][4] = {};
#pragma unroll
    for (int ks = 0; ks < 4; ++ks) {
        int kb = ks * 32 + g * 8;
        f16x8 a[4];
#pragma unroll
        for (int mt = 0; mt < 4; ++mt) {
            int r = mt * 16 + li;
            a[mt] = *(const f16x8*)&Xs[r][SWZ(r, kb)];
        }
#pragma unroll
        for (int nt = 0; nt < 4; ++nt) {
            int n = colW + nt * 16 + li;
            f16x8 b = *(const f16x8*)(L1T + n * 128 + kb);
#pragma unroll
            for (int mt = 0; mt < 4; ++mt)
                acc[mt][nt] = __builtin_amdgcn_mfma_f32_16x16x32_f16(a[mt], b, acc[mt][nt], 0, 0, 0);
        }
    }
#pragma unroll
    for (int nt = 0; nt < 4; ++nt) {
        int col = colW + nt * 16 + li;
        float bb = bl1[col];
#pragma unroll
        for (int mt = 0; mt < 4; ++mt)
#pragma unroll
            for (int r4 = 0; r4 < 4; ++r4) {
                int row = mt * 16 + g * 4 + r4;
                H1s[row][SWZ(row, col)] = (_Float16)fmaxf(acc[mt][nt][r4] + bb, 0.f);
            }
    }
    __syncthreads();

    // GEMM2: H2 = relu(H1 @ L2 + bl2); fold L3 dot
    f32x4 acc2[4][4] = {};
#pragma unroll
    for (int ks = 0; ks < 8; ++ks) {
        int kb = ks * 32 + g * 8;
        f16x8 a[4];
#pragma unroll
        for (int mt = 0; mt < 4; ++mt) {
            int r = mt * 16 + li;
            a[mt] = *(const f16x8*)&H1s[r][SWZ(r, kb)];
        }
#pragma unroll
        for (int nt = 0; nt < 4; ++nt) {
            int n = colW + nt * 16 + li;
            f16x8 b = *(const f16x8*)(L2T + n * 256 + kb);
#pragma unroll
            for (int mt = 0; mt < 4; ++mt)
                acc2[mt][nt] = __builtin_amdgcn_mfma_f32_16x16x32_f16(a[mt], b, acc2[mt][nt], 0, 0, 0);
        }
    }
    float part[4][4] = {};
#pragma unroll
    for (int nt = 0; nt < 4; ++nt) {
        int col = colW + nt * 16 + li;
        float bb = bl2[col];
        float l3v = L3[col];
#pragma unroll
        for (int mt = 0; mt < 4; ++mt)
#pragma unroll
            for (int r4 = 0; r4 < 4; ++r4)
                part[mt][r4] += fmaxf(acc2[mt][nt][r4] + bb, 0.f) * l3v;
    }
#pragma unroll
    for (int mt = 0; mt < 4; ++mt)
#pragma unroll
        for (int r4 = 0; r4 < 4; ++r4) {
            float p = part[mt][r4];
            p += __shfl_xor(p, 1, 64);
            p += __shfl_xor(p, 2, 64);
            p += __shfl_xor(p, 4, 64);
            p += __shfl_xor(p, 8, 64);
            if (li == 0) Hred[w][mt * 16 + g * 4 + r4] = p;
        }
    __syncthreads();
    if (t < 64) {
        int gr = rowBase + t;
        if (gr < NN)
            sacc[gr] += Hred[0][t] + Hred[1][t] + Hred[2][t] + Hred[3][t] + bl3[0];
    }
}

// ---------------- Y[M x 128] = X[M x 128] @ W (WT fp16 N-major), fp16 out ----------------
__global__ __launch_bounds__(256) void gemm128_mfma_k(const _Float16* __restrict__ X,
                                                      const _Float16* __restrict__ WT,
                                                      _Float16* __restrict__ Y) {
    __shared__ _Float16 Xs[64][128];
    int t = threadIdx.x;
    int w = t >> 6, l = t & 63;
    int g = l >> 4, li = l & 15;
    int rowBase = blockIdx.x * 64;
#pragma unroll
    for (int i = 0; i < 4; ++i) {
        int idx = t + i * 256;
        int r = idx >> 4, c8 = idx & 15;
        int gr = rowBase + r;
        f16x8 v = (gr < NN) ? *(const f16x8*)(X + (size_t)gr * 128 + c8 * 8)
                            : (f16x8)(_Float16)0.f;
        *(f16x8*)&Xs[r][SWZ(r, c8 * 8)] = v;
    }
    __syncthreads();
    int colW = w * 32;
    f32x4 acc[4][2] = {};
#pragma unroll
    for (int ks = 0; ks < 4; ++ks) {
        int kb = ks * 32 + g * 8;
        f16x8 a[4];
#pragma unroll
        for (int mt = 0; mt < 4; ++mt) {
            int r = mt * 16 + li;
            a[mt] = *(const f16x8*)&Xs[r][SWZ(r, kb)];
        }
#pragma unroll
        for (int nt = 0; nt < 2; ++nt) {
            int n = colW + nt * 16 + li;
            f16x8 b = *(const f16x8*)(WT + n * 128 + kb);
#pragma unroll
            for (int mt = 0; mt < 4; ++mt)
                acc[mt][nt] = __builtin_amdgcn_mfma_f32_16x16x32_f16(a[mt], b, acc[mt][nt], 0, 0, 0);
        }
    }
#pragma unroll
    for (int mt = 0; mt < 4; ++mt)
#pragma unroll
        for (int nt = 0; nt < 2; ++nt)
#pragma unroll
            for (int r4 = 0; r4 < 4; ++r4) {
                int gr = rowBase + mt * 16 + g * 4 + r4;
                if (gr < NN)
                    Y[(size_t)gr * 128 + colW + nt * 16 + li] = (_Float16)acc[mt][nt][r4];
            }
}

__global__ void score_store_k(const float* __restrict__ sacc, float* __restrict__ dst) {
    int i = blockIdx.x * 256 + threadIdx.x;
    if (i < NN) dst[i] = sacc[i] * (1.f / 7.f);
}

__global__ void final_mul_k(const float* __restrict__ sacc, const float* __restrict__ score1,
                            float* __restrict__ out) {
    int i = blockIdx.x * 256 + threadIdx.x;
    if (i < NN) out[i] = score1[i] * (sacc[i] * (1.f / 7.f));
}

// ---------------- host orchestration ----------------
extern "C" void kernel_launch(void* const* d_in, const int* in_sizes, int n_in,
                              void* d_out, int out_size, void* d_ws, size_t ws_size,
                              hipStream_t stream) {
    const int* asrc[2] = {(const int*)d_in[0], (const int*)d_in[3]};
    const int* adst[2] = {(const int*)d_in[1], (const int*)d_in[4]};
    const float* aw[2] = {(const float*)d_in[2], (const float*)d_in[5]};
    const float* W1 = (const float*)d_in[6];
    const float* b1 = (const float*)d_in[7];
    const float* Wk[5] = {(const float*)d_in[8], (const float*)d_in[10], (const float*)d_in[12],
                          (const float*)d_in[14], (const float*)d_in[16]};
    const float* bk[5] = {(const float*)d_in[9], (const float*)d_in[11], (const float*)d_in[13],
                          (const float*)d_in[15], (const float*)d_in[17]};
    const float* L1 = (const float*)d_in[18];
    const float* bl1 = (const float*)d_in[19];
    const float* L2 = (const float*)d_in[20];
    const float* bl2 = (const float*)d_in[21];
    const float* L3 = (const float*)d_in[22];
    const float* bl3 = (const float*)d_in[23];
    float* out = (float*)d_out;

    // workspace layout (16B-aligned sections)
    char* p = (char*)d_ws;
    _Float16* L1T = (_Float16*)p; p += 65536;       // 256x128
    _Float16* L2T = (_Float16*)p; p += 131072;      // 256x256
    _Float16* WkT = (_Float16*)p; p += 163840;      // 5 x 128x128
    _Float16* W1h = (_Float16*)p; p += NNH * 2;     // fp16 W1
    _Float16* tmp = (_Float16*)p; p += NNH * 2;     // gemm out
    _Float16* xbuf = (_Float16*)p; p += 6 * NNH * 2; // x1..x6
    float* sacc = (float*)p; p += (size_t)NN * 4;
    float* score1 = (float*)p; p += (size_t)NN * 4;
    int2* ep = (int2*)p; p += (size_t)NE * 8;       // packed edges
    int* rowptr = (int*)p; p += (size_t)(NN + 1) * 4;
    int* cursor = (int*)p; p += (size_t)NN * 4;
    int* bsum = (int*)p; p += 512;

    const int GE = (NE + 255) / 256;
    const int GN = (NN + 255) / 256;
    const int GS = (NN + 3) / 4;
    const int GM = (NN + 63) / 64;       // 1563
    const int NB = (NN + 1023) / 1024;   // 98

    // ---- one-time weight conversion ----
    convT_k<<<(128 * 256 + 255) / 256, 256, 0, stream>>>(L1, L1T, 128, 256);
    convT_k<<<(256 * 256 + 255) / 256, 256, 0, stream>>>(L2, L2T, 256, 256);
    for (int l = 0; l < 5; ++l)
        convT_k<<<(128 * 128 + 255) / 256, 256, 0, stream>>>(Wk[l], WkT + (size_t)l * 16384, 128, 128);
    conv4_k<<<(NN * HID / 4 + 255) / 256, 256, 0, stream>>>(W1, W1h, NN * HID / 4);

    for (int br = 0; br < 2; ++br) {
        // ---- build CSR (packed records) ----
        zero_k<<<GN, 256, 0, stream>>>(rowptr, NN + 1);
        hist_k<<<GE, 256, 0, stream>>>(adst[br], rowptr);
        scanA_k<<<NB, 1024, 0, stream>>>(rowptr, bsum, NN);
        scanB_k<<<1, 64, 0, stream>>>(bsum, rowptr, NB, NN);
        scanC_k<<<GN, 256, 0, stream>>>(rowptr, cursor, bsum, NN);
        scatter_k<<<GE, 256, 0, stream>>>(asrc[br], adst[br], aw[br], cursor, ep);

        zero_k<<<GN, 256, 0, stream>>>((int*)sacc, NN);

        // ---- layer 1 ----
        spmm_k<true><<<GS, 256, 0, stream>>>(W1h, rowptr, ep, b1, xbuf);
        mlp_fused_k<false><<<GM, 256, 0, stream>>>(xbuf, L1T, bl1, L2T, bl2, L3, bl3, sacc);

        // ---- layers 2..6 ----
        for (int l = 0; l < 5; ++l) {
            gemm128_mfma_k<<<GM, 256, 0, stream>>>(xbuf + (size_t)l * NNH, WkT + (size_t)l * 16384, tmp);
            _Float16* xo = xbuf + (size_t)(l + 1) * NNH;
            if (l < 4)
                spmm_k<true><<<GS, 256, 0, stream>>>(tmp, rowptr, ep, bk[l], xo);
            else
                spmm_k<false><<<GS, 256, 0, stream>>>(tmp, rowptr, ep, bk[l], xo);
            mlp_fused_k<false><<<GM, 256, 0, stream>>>(xo, L1T, bl1, L2T, bl2, L3, bl3, sacc);
        }

        // ---- mlp(x7 = x1+...+x6) ----
        mlp_fused_k<true><<<GM, 256, 0, stream>>>(xbuf, L1T, bl1, L2T, bl2, L3, bl3, sacc);

        if (br == 0)
            score_store_k<<<GN, 256, 0, stream>>>(sacc, score1);
        else
            final_mul_k<<<GN, 256, 0, stream>>>(sacc, score1, out);
    }
}

// Round 6
// 2797.232 us; speedup vs baseline: 3.5596x; 1.0275x over previous
//
#include <hip/hip_runtime.h>

#define NN 100000
#define NE 3200000
#define HID 128
#define NNH ((size_t)NN * HID)

typedef __attribute__((ext_vector_type(8))) _Float16 f16x8;
typedef __attribute__((ext_vector_type(4))) _Float16 f16x4;
typedef __attribute__((ext_vector_type(4))) float f32x4;

// swizzle in element units: XOR elem bits 3..5 with row bits 0..2
#define SWZ(row, k) ((k) ^ (((row) & 7) << 3))

// ---------------- small utility kernels ----------------
__global__ void zero_k(int* p, int n) {
    int i = blockIdx.x * 256 + threadIdx.x;
    if (i < n) p[i] = 0;
}

__global__ void hist_k(const int* __restrict__ dst, int* __restrict__ cnt) {
    int e = blockIdx.x * 256 + threadIdx.x;
    if (e < NE) atomicAdd(&cnt[dst[e]], 1);
}

// ---- multi-block exclusive scan of rowptr[0..n) ----
__global__ __launch_bounds__(1024) void scanA_k(int* __restrict__ rowptr, int* __restrict__ bsum, int n) {
    __shared__ int wsum[16];
    int tid = threadIdx.x;
    int lane = tid & 63, wid = tid >> 6;
    int idx = blockIdx.x * 1024 + tid;
    int v = (idx < n) ? rowptr[idx] : 0;
    int s = v;
#pragma unroll
    for (int o = 1; o < 64; o <<= 1) {
        int t = __shfl_up(s, o, 64);
        if (lane >= o) s += t;
    }
    if (lane == 63) wsum[wid] = s;
    __syncthreads();
    if (wid == 0) {
        int ws = (lane < 16) ? wsum[lane] : 0;
#pragma unroll
        for (int o = 1; o < 16; o <<= 1) {
            int t = __shfl_up(ws, o, 64);
            if (lane >= o) ws += t;
        }
        if (lane < 16) wsum[lane] = ws;
    }
    __syncthreads();
    int woff = (wid == 0) ? 0 : wsum[wid - 1];
    if (idx < n) rowptr[idx] = woff + s - v;
    if (tid == 0) bsum[blockIdx.x] = wsum[15];
}

__global__ void scanB_k(int* __restrict__ bsum, int* __restrict__ rowptr, int nb, int n) {
    if (threadIdx.x == 0) {
        int run = 0;
        for (int i = 0; i < nb; ++i) {
            int t = bsum[i];
            bsum[i] = run;
            run += t;
        }
        rowptr[n] = run;
    }
}

__global__ void scanC_k(int* __restrict__ rowptr, int* __restrict__ cursor,
                        const int* __restrict__ bsum, int n) {
    int idx = blockIdx.x * 256 + threadIdx.x;
    if (idx < n) {
        int v = rowptr[idx] + bsum[idx >> 10];
        rowptr[idx] = v;
        cursor[idx] = v;
    }
}

// packed scatter: one 4B record (src:17 | fp16(w) sans sign:15) per edge
__global__ void scatter_k(const int* __restrict__ src, const int* __restrict__ dst,
                          const float* __restrict__ w, int* __restrict__ cursor,
                          unsigned* __restrict__ ep) {
    int e = blockIdx.x * 256 + threadIdx.x;
    if (e < NE) {
        int d = dst[e];
        int pos = atomicAdd(&cursor[d], 1);
        ushort hb = __builtin_bit_cast(ushort, (_Float16)w[e]);  // w >= 0 -> bit15 == 0
        ep[pos] = ((unsigned)src[e] << 15) | (unsigned)hb;
    }
}

// transpose + fp16 convert: WT[n][k] = h(W[k][n]);  W is K x N row-major
__global__ void convT_k(const float* __restrict__ W, _Float16* __restrict__ WT, int K, int N) {
    int idx = blockIdx.x * 256 + threadIdx.x;
    if (idx < K * N) {
        int k = idx / N, n = idx % N;
        WT[n * K + k] = (_Float16)W[idx];
    }
}

// flat fp32 -> fp16 convert (4-wide)
__global__ void conv4_k(const float* __restrict__ A, _Float16* __restrict__ B, int n4) {
    int i = blockIdx.x * 256 + threadIdx.x;
    if (i < n4) {
        float4 v = ((const float4*)A)[i];
        f16x4 h;
        h.x = (_Float16)v.x; h.y = (_Float16)v.y; h.z = (_Float16)v.z; h.w = (_Float16)v.w;
        ((f16x4*)B)[i] = h;
    }
}

// ---------------- SpMM (CSR packed u32, fp16 rows) ----------------
// one wave per dst row; 4 quarter-waves over edges; lane li: cols li*8..li*8+7.
// EPI: apply bias+relu+l2norm (layer 1); else raw fp16 aggregate store.
template <bool EPI>
__global__ void spmm_k(const _Float16* __restrict__ x, const int* __restrict__ rowptr,
                       const unsigned* __restrict__ ep, const float* __restrict__ bias,
                       _Float16* __restrict__ outx) {
    int row = blockIdx.x * 4 + (threadIdx.x >> 6);
    int l = threadIdx.x & 63;
    int q = l >> 4, li = l & 15;
    if (row >= NN) return;
    int e0 = rowptr[row], e1 = rowptr[row + 1];
    float acc[8] = {};
#pragma unroll 4
    for (int e = e0 + q; e < e1; e += 4) {
        unsigned r = ep[e];
        int s = r >> 15;
        float w = (float)__builtin_bit_cast(_Float16, (ushort)(r & 0x7FFFu));
        f16x8 v = *(const f16x8*)(x + (size_t)s * HID + li * 8);
#pragma unroll
        for (int j = 0; j < 8; ++j) acc[j] += w * (float)v[j];
    }
#pragma unroll
    for (int j = 0; j < 8; ++j) {
        acc[j] += __shfl_xor(acc[j], 16, 64);
        acc[j] += __shfl_xor(acc[j], 32, 64);
    }
    if (EPI) {
        const float4* bp = (const float4*)(bias + li * 8);
        float4 b0 = bp[0], b1 = bp[1];
        acc[0] = fmaxf(acc[0] + b0.x, 0.f); acc[1] = fmaxf(acc[1] + b0.y, 0.f);
        acc[2] = fmaxf(acc[2] + b0.z, 0.f); acc[3] = fmaxf(acc[3] + b0.w, 0.f);
        acc[4] = fmaxf(acc[4] + b1.x, 0.f); acc[5] = fmaxf(acc[5] + b1.y, 0.f);
        acc[6] = fmaxf(acc[6] + b1.z, 0.f); acc[7] = fmaxf(acc[7] + b1.w, 0.f);
        float ss = 0.f;
#pragma unroll
        for (int j = 0; j < 8; ++j) ss += acc[j] * acc[j];
        ss += __shfl_xor(ss, 1, 64);
        ss += __shfl_xor(ss, 2, 64);
        ss += __shfl_xor(ss, 4, 64);
        ss += __shfl_xor(ss, 8, 64);
        float sc = 1.0f / fmaxf(sqrtf(ss), 1e-12f);
#pragma unroll
        for (int j = 0; j < 8; ++j) acc[j] *= sc;
    }
    if (q == 0) {
        f16x8 ho;
#pragma unroll
        for (int j = 0; j < 8; ++j) ho[j] = (_Float16)acc[j];
        *(f16x8*)(outx + (size_t)row * HID + li * 8) = ho;
    }
}

// ---------------- fused transform + MLP ----------------
// x_next = l2norm?(relu(Y @ W + bw)); Xo = x_next; sacc += mlp(x_next)
template <bool NORM>
__global__ __launch_bounds__(256) void trans_mlp_k(
    const _Float16* __restrict__ Y,     // NN x 128 raw aggregate
    const _Float16* __restrict__ WT,    // 128 x 128 (N-major)
    const float* __restrict__ bw,       // 128
    _Float16* __restrict__ Xo,          // NN x 128 out
    const _Float16* __restrict__ L1T, const float* __restrict__ bl1,
    const _Float16* __restrict__ L2T, const float* __restrict__ bl2,
    const float* __restrict__ L3, const float* __restrict__ bl3,
    float* __restrict__ sacc) {
    __shared__ _Float16 Xs[64][128];
    __shared__ _Float16 H1s[64][256];
    __shared__ float red[4][64];
    int t = threadIdx.x;
    int w = t >> 6, l = t & 63;
    int g = l >> 4, li = l & 15;
    int rowBase = blockIdx.x * 64;

    // stage y
#pragma unroll
    for (int i = 0; i < 4; ++i) {
        int idx = t + i * 256;
        int r = idx >> 4, c8 = idx & 15;
        int gr = rowBase + r;
        f16x8 v = (gr < NN) ? *(const f16x8*)(Y + (size_t)gr * 128 + c8 * 8)
                            : (f16x8)(_Float16)0.f;
        *(f16x8*)&Xs[r][SWZ(r, c8 * 8)] = v;
    }
    __syncthreads();

    // GEMM_W: z = y @ W ; wave owns cols cW..cW+31
    int cW = w * 32;
    f32x4 accw[4][2] = {};
#pragma unroll
    for (int ks = 0; ks < 4; ++ks) {
        int kb = ks * 32 + g * 8;
        f16x8 a[4];
#pragma unroll
        for (int mt = 0; mt < 4; ++mt) {
            int r = mt * 16 + li;
            a[mt] = *(const f16x8*)&Xs[r][SWZ(r, kb)];
        }
#pragma unroll
        for (int nt = 0; nt < 2; ++nt) {
            f16x8 b = *(const f16x8*)(WT + (size_t)(cW + nt * 16 + li) * 128 + kb);
#pragma unroll
            for (int mt = 0; mt < 4; ++mt)
                accw[mt][nt] = __builtin_amdgcn_mfma_f32_16x16x32_f16(a[mt], b, accw[mt][nt], 0, 0, 0);
        }
    }
    // bias + relu
    float vv[4][2][4];
    float b0 = bw[cW + li], b1v = bw[cW + 16 + li];
#pragma unroll
    for (int mt = 0; mt < 4; ++mt)
#pragma unroll
        for (int r4 = 0; r4 < 4; ++r4) {
            vv[mt][0][r4] = fmaxf(accw[mt][0][r4] + b0, 0.f);
            vv[mt][1][r4] = fmaxf(accw[mt][1][r4] + b1v, 0.f);
        }
    if (NORM) {
#pragma unroll
        for (int mt = 0; mt < 4; ++mt)
#pragma unroll
            for (int r4 = 0; r4 < 4; ++r4) {
                float ps = vv[mt][0][r4] * vv[mt][0][r4] + vv[mt][1][r4] * vv[mt][1][r4];
                ps += __shfl_xor(ps, 1, 64);
                ps += __shfl_xor(ps, 2, 64);
                ps += __shfl_xor(ps, 4, 64);
                ps += __shfl_xor(ps, 8, 64);
                if (li == 0) red[w][mt * 16 + g * 4 + r4] = ps;
            }
        __syncthreads();
        if (t < 64) {
            float s = red[0][t] + red[1][t] + red[2][t] + red[3][t];
            red[0][t] = 1.f / fmaxf(sqrtf(s), 1e-12f);
        }
        __syncthreads();
    } else {
        __syncthreads();  // all y reads done before Xs overwrite
    }
    // scale, write x_next to LDS (swizzled) + global
#pragma unroll
    for (int mt = 0; mt < 4; ++mt)
#pragma unroll
        for (int r4 = 0; r4 < 4; ++r4) {
            int row = mt * 16 + g * 4 + r4;
            float sc = NORM ? red[0][row] : 1.f;
            _Float16 h0 = (_Float16)(vv[mt][0][r4] * sc);
            _Float16 h1 = (_Float16)(vv[mt][1][r4] * sc);
            Xs[row][SWZ(row, cW + li)] = h0;
            Xs[row][SWZ(row, cW + 16 + li)] = h1;
            int gr = rowBase + row;
            if (gr < NN) {
                Xo[(size_t)gr * 128 + cW + li] = h0;
                Xo[(size_t)gr * 128 + cW + 16 + li] = h1;
            }
        }
    __syncthreads();

    // ---- MLP on Xs ----
    int cM = w * 64;
    f32x4 acc[4][4] = {};
#pragma unroll
    for (int ks = 0; ks < 4; ++ks) {
        int kb = ks * 32 + g * 8;
        f16x8 a[4];
#pragma unroll
        for (int mt = 0; mt < 4; ++mt) {
            int r = mt * 16 + li;
            a[mt] = *(const f16x8*)&Xs[r][SWZ(r, kb)];
        }
#pragma unroll
        for (int nt = 0; nt < 4; ++nt) {
            int n = cM + nt * 16 + li;
            f16x8 b = *(const f16x8*)(L1T + (size_t)n * 128 + kb);
#pragma unroll
            for (int mt = 0; mt < 4; ++mt)
                acc[mt][nt] = __builtin_amdgcn_mfma_f32_16x16x32_f16(a[mt], b, acc[mt][nt], 0, 0, 0);
        }
    }
#pragma unroll
    for (int nt = 0; nt < 4; ++nt) {
        int col = cM + nt * 16 + li;
        float bb = bl1[col];
#pragma unroll
        for (int mt = 0; mt < 4; ++mt)
#pragma unroll
            for (int r4 = 0; r4 < 4; ++r4) {
                int row = mt * 16 + g * 4 + r4;
                H1s[row][SWZ(row, col)] = (_Float16)fmaxf(acc[mt][nt][r4] + bb, 0.f);
            }
    }
    __syncthreads();

    f32x4 acc2[4][4] = {};
#pragma unroll
    for (int ks = 0; ks < 8; ++ks) {
        int kb = ks * 32 + g * 8;
        f16x8 a[4];
#pragma unroll
        for (int mt = 0; mt < 4; ++mt) {
            int r = mt * 16 + li;
            a[mt] = *(const f16x8*)&H1s[r][SWZ(r, kb)];
        }
#pragma unroll
        for (int nt = 0; nt < 4; ++nt) {
            int n = cM + nt * 16 + li;
            f16x8 b = *(const f16x8*)(L2T + (size_t)n * 256 + kb);
#pragma unroll
            for (int mt = 0; mt < 4; ++mt)
                acc2[mt][nt] = __builtin_amdgcn_mfma_f32_16x16x32_f16(a[mt], b, acc2[mt][nt], 0, 0, 0);
        }
    }
    float part[4][4] = {};
#pragma unroll
    for (int nt = 0; nt < 4; ++nt) {
        int col = cM + nt * 16 + li;
        float bb = bl2[col];
        float l3v = L3[col];
#pragma unroll
        for (int mt = 0; mt < 4; ++mt)
#pragma unroll
            for (int r4 = 0; r4 < 4; ++r4)
                part[mt][r4] += fmaxf(acc2[mt][nt][r4] + bb, 0.f) * l3v;
    }
#pragma unroll
    for (int mt = 0; mt < 4; ++mt)
#pragma unroll
        for (int r4 = 0; r4 < 4; ++r4) {
            float p = part[mt][r4];
            p += __shfl_xor(p, 1, 64);
            p += __shfl_xor(p, 2, 64);
            p += __shfl_xor(p, 4, 64);
            p += __shfl_xor(p, 8, 64);
            if (li == 0) red[w][mt * 16 + g * 4 + r4] = p;
        }
    __syncthreads();
    if (t < 64) {
        int gr = rowBase + t;
        if (gr < NN)
            sacc[gr] += red[0][t] + red[1][t] + red[2][t] + red[3][t] + bl3[0];
    }
}

// ---------------- plain MLP: sacc (+)= mlp(X) ----------------
// SUM6: X = sum of 6 stacked fp16 buffers; INIT: store instead of accumulate.
template <bool SUM6, bool INIT>
__global__ __launch_bounds__(256) void mlp_fused_k(
    const _Float16* __restrict__ X,
    const _Float16* __restrict__ L1T, const float* __restrict__ bl1,
    const _Float16* __restrict__ L2T, const float* __restrict__ bl2,
    const float* __restrict__ L3, const float* __restrict__ bl3,
    float* __restrict__ sacc) {
    __shared__ _Float16 Xs[64][128];
    __shared__ _Float16 H1s[64][256];
    __shared__ float red[4][64];
    int t = threadIdx.x;
    int w = t >> 6, l = t & 63;
    int g = l >> 4, li = l & 15;
    int rowBase = blockIdx.x * 64;

#pragma unroll
    for (int i = 0; i < 4; ++i) {
        int idx = t + i * 256;
        int r = idx >> 4, c8 = idx & 15;
        int gr = rowBase + r;
        if (SUM6) {
            float s[8] = {};
            if (gr < NN) {
#pragma unroll
                for (int l6 = 0; l6 < 6; ++l6) {
                    f16x8 v = *(const f16x8*)(X + (size_t)l6 * NNH + (size_t)gr * HID + c8 * 8);
#pragma unroll
                    for (int j = 0; j < 8; ++j) s[j] += (float)v[j];
                }
            }
            f16x8 hv;
#pragma unroll
            for (int j = 0; j < 8; ++j) hv[j] = (_Float16)s[j];
            *(f16x8*)&Xs[r][SWZ(r, c8 * 8)] = hv;
        } else {
            f16x8 v = (gr < NN) ? *(const f16x8*)(X + (size_t)gr * HID + c8 * 8)
                                : (f16x8)(_Float16)0.f;
            *(f16x8*)&Xs[r][SWZ(r, c8 * 8)] = v;
        }
    }
    __syncthreads();

    int cM = w * 64;
    f32x4 acc[4][4] = {};
#pragma unroll
    for (int ks = 0; ks < 4; ++ks) {
        int kb = ks * 32 + g * 8;
        f16x8 a[4];
#pragma unroll
        for (int mt = 0; mt < 4; ++mt) {
            int r = mt * 16 + li;
            a[mt] = *(const f16x8*)&Xs[r][SWZ(r, kb)];
        }
#pragma unroll
        for (int nt = 0; nt < 4; ++nt) {
            int n = cM + nt * 16 + li;
            f16x8 b = *(const f16x8*)(L1T + (size_t)n * 128 + kb);
#pragma unroll
            for (int mt = 0; mt < 4; ++mt)
                acc[mt][nt] = __builtin_amdgcn_mfma_f32_16x16x32_f16(a[mt], b, acc[mt][nt], 0, 0, 0);
        }
    }
#pragma unroll
    for (int nt = 0; nt < 4; ++nt) {
        int col = cM + nt * 16 + li;
        float bb = bl1[col];
#pragma unroll
        for (int mt = 0; mt < 4; ++mt)
#pragma unroll
            for (int r4 = 0; r4 < 4; ++r4) {
                int row = mt * 16 + g * 4 + r4;
                H1s[row][SWZ(row, col)] = (_Float16)fmaxf(acc[mt][nt][r4] + bb, 0.f);
            }
    }
    __syncthreads();

    f32x4 acc2[4][4] = {};
#pragma unroll
    for (int ks = 0; ks < 8; ++ks) {
        int kb = ks * 32 + g * 8;
        f16x8 a[4];
#pragma unroll
        for (int mt = 0; mt < 4; ++mt) {
            int r = mt * 16 + li;
            a[mt] = *(const f16x8*)&H1s[r][SWZ(r, kb)];
        }
#pragma unroll
        for (int nt = 0; nt < 4; ++nt) {
            int n = cM + nt * 16 + li;
            f16x8 b = *(const f16x8*)(L2T + (size_t)n * 256 + kb);
#pragma unroll
            for (int mt = 0; mt < 4; ++mt)
                acc2[mt][nt] = __builtin_amdgcn_mfma_f32_16x16x32_f16(a[mt], b, acc2[mt][nt], 0, 0, 0);
        }
    }
    float part[4][4] = {};
#pragma unroll
    for (int nt = 0; nt < 4; ++nt) {
        int col = cM + nt * 16 + li;
        float bb = bl2[col];
        float l3v = L3[col];
#pragma unroll
        for (int mt = 0; mt < 4; ++mt)
#pragma unroll
            for (int r4 = 0; r4 < 4; ++r4)
                part[mt][r4] += fmaxf(acc2[mt][nt][r4] + bb, 0.f) * l3v;
    }
#pragma unroll
    for (int mt = 0; mt < 4; ++mt)
#pragma unroll
        for (int r4 = 0; r4 < 4; ++r4) {
            float p = part[mt][r4];
            p += __shfl_xor(p, 1, 64);
            p += __shfl_xor(p, 2, 64);
            p += __shfl_xor(p, 4, 64);
            p += __shfl_xor(p, 8, 64);
            if (li == 0) red[w][mt * 16 + g * 4 + r4] = p;
        }
    __syncthreads();
    if (t < 64) {
        int gr = rowBase + t;
        if (gr < NN) {
            float s = red[0][t] + red[1][t] + red[2][t] + red[3][t] + bl3[0];
            if (INIT) sacc[gr] = s; else sacc[gr] += s;
        }
    }
}

__global__ void score_store_k(const float* __restrict__ sacc, float* __restrict__ dst) {
    int i = blockIdx.x * 256 + threadIdx.x;
    if (i < NN) dst[i] = sacc[i] * (1.f / 7.f);
}

__global__ void final_mul_k(const float* __restrict__ sacc, const float* __restrict__ score1,
                            float* __restrict__ out) {
    int i = blockIdx.x * 256 + threadIdx.x;
    if (i < NN) out[i] = score1[i] * (sacc[i] * (1.f / 7.f));
}

// ---------------- host orchestration ----------------
extern "C" void kernel_launch(void* const* d_in, const int* in_sizes, int n_in,
                              void* d_out, int out_size, void* d_ws, size_t ws_size,
                              hipStream_t stream) {
    const int* asrc[2] = {(const int*)d_in[0], (const int*)d_in[3]};
    const int* adst[2] = {(const int*)d_in[1], (const int*)d_in[4]};
    const float* aw[2] = {(const float*)d_in[2], (const float*)d_in[5]};
    const float* W1 = (const float*)d_in[6];
    const float* b1 = (const float*)d_in[7];
    const float* Wk[5] = {(const float*)d_in[8], (const float*)d_in[10], (const float*)d_in[12],
                          (const float*)d_in[14], (const float*)d_in[16]};
    const float* bk[5] = {(const float*)d_in[9], (const float*)d_in[11], (const float*)d_in[13],
                          (const float*)d_in[15], (const float*)d_in[17]};
    const float* L1 = (const float*)d_in[18];
    const float* bl1 = (const float*)d_in[19];
    const float* L2 = (const float*)d_in[20];
    const float* bl2 = (const float*)d_in[21];
    const float* L3 = (const float*)d_in[22];
    const float* bl3 = (const float*)d_in[23];
    float* out = (float*)d_out;

    // workspace layout (16B-aligned sections)
    char* p = (char*)d_ws;
    _Float16* L1T = (_Float16*)p; p += 65536;        // 256x128
    _Float16* L2T = (_Float16*)p; p += 131072;       // 256x256
    _Float16* WkT = (_Float16*)p; p += 163840;       // 5 x 128x128
    _Float16* W1h = (_Float16*)p; p += NNH * 2;      // fp16 W1
    _Float16* tmp = (_Float16*)p; p += NNH * 2;      // raw aggregate y
    _Float16* xbuf = (_Float16*)p; p += 6 * NNH * 2; // x1..x6
    float* sacc = (float*)p; p += (size_t)NN * 4;
    float* score1 = (float*)p; p += (size_t)NN * 4;
    unsigned* ep = (unsigned*)p; p += (size_t)NE * 4; // packed edges
    int* rowptr = (int*)p; p += (size_t)(NN + 1) * 4;
    int* cursor = (int*)p; p += (size_t)NN * 4;
    int* bsum = (int*)p; p += 512;

    const int GE = (NE + 255) / 256;
    const int GN = (NN + 255) / 256;
    const int GS = (NN + 3) / 4;
    const int GM = (NN + 63) / 64;       // 1563
    const int NB = (NN + 1023) / 1024;   // 98

    // ---- one-time weight conversion ----
    convT_k<<<(128 * 256 + 255) / 256, 256, 0, stream>>>(L1, L1T, 128, 256);
    convT_k<<<(256 * 256 + 255) / 256, 256, 0, stream>>>(L2, L2T, 256, 256);
    for (int l = 0; l < 5; ++l)
        convT_k<<<(128 * 128 + 255) / 256, 256, 0, stream>>>(Wk[l], WkT + (size_t)l * 16384, 128, 128);
    conv4_k<<<(NN * HID / 4 + 255) / 256, 256, 0, stream>>>(W1, W1h, NN * HID / 4);

    for (int br = 0; br < 2; ++br) {
        // ---- build CSR (packed u32 records) ----
        zero_k<<<GN, 256, 0, stream>>>(rowptr, NN + 1);
        hist_k<<<GE, 256, 0, stream>>>(adst[br], rowptr);
        scanA_k<<<NB, 1024, 0, stream>>>(rowptr, bsum, NN);
        scanB_k<<<1, 64, 0, stream>>>(bsum, rowptr, NB, NN);
        scanC_k<<<GN, 256, 0, stream>>>(rowptr, cursor, bsum, NN);
        scatter_k<<<GE, 256, 0, stream>>>(asrc[br], adst[br], aw[br], cursor, ep);

        // ---- layer 1: x1 = norm(relu(adj@W1 + b1)); sacc = mlp(x1) ----
        spmm_k<true><<<GS, 256, 0, stream>>>(W1h, rowptr, ep, b1, xbuf);
        mlp_fused_k<false, true><<<GM, 256, 0, stream>>>(xbuf, L1T, bl1, L2T, bl2, L3, bl3, sacc);

        // ---- layers 2..6: y = adj@x_l ; x_{l+1} = norm?(relu(y@W+b)); sacc += mlp ----
        for (int l = 0; l < 5; ++l) {
            spmm_k<false><<<GS, 256, 0, stream>>>(xbuf + (size_t)l * NNH, rowptr, ep, b1, tmp);
            _Float16* xo = xbuf + (size_t)(l + 1) * NNH;
            if (l < 4)
                trans_mlp_k<true><<<GM, 256, 0, stream>>>(tmp, WkT + (size_t)l * 16384, bk[l], xo,
                                                          L1T, bl1, L2T, bl2, L3, bl3, sacc);
            else
                trans_mlp_k<false><<<GM, 256, 0, stream>>>(tmp, WkT + (size_t)l * 16384, bk[l], xo,
                                                           L1T, bl1, L2T, bl2, L3, bl3, sacc);
        }

        // ---- mlp(x7 = x1+...+x6) ----
        mlp_fused_k<true, false><<<GM, 256, 0, stream>>>(xbuf, L1T, bl1, L2T, bl2, L3, bl3, sacc);

        if (br == 0)
            score_store_k<<<GN, 256, 0, stream>>>(sacc, score1);
        else
            final_mul_k<<<GN, 256, 0, stream>>>(sacc, score1, out);
    }
}